// Round 8
// baseline (358.324 us; speedup 1.0000x reference)
//
#include <hip/hip_runtime.h>
#include <hip/hip_bf16.h>
#include <cmath>

#define D_MODEL   1024
#define N_HEAD    16
#define HEAD_DIM  64
#define SEQ_LEN   2048
#define NBATCH    2
#define M_TOTAL   (NBATCH * SEQ_LEN)   // 4096
#define IN_DIM    512
#define MLP_HID   4096

typedef __attribute__((ext_vector_type(8))) short short8;
typedef __attribute__((ext_vector_type(4))) short short4v;
typedef __attribute__((ext_vector_type(4))) float floatx4;

typedef const __attribute__((address_space(1))) void* gas_ptr;
typedef __attribute__((address_space(3))) void* las_ptr;

__device__ __forceinline__ void async_copy16(const void* g, void* l) {
  __builtin_amdgcn_global_load_lds((gas_ptr)g, (las_ptr)l, 16, 0, 0);
}

// XCD-aware bijective block swizzle (T1). Hardware round-robins consecutive
// dispatch ids across the 8 XCDs; remapping id -> (id&7)*q + id>>3 gives each
// XCD a CONTIGUOUS chunk of tiles, so panel-sharing neighbors hit the same
// 4MB L2 instead of re-fetching from L3/HBM. Requires nwg % 8 == 0 (all our
// per-z-slice grids: 256/768/32). z-slices shift dispatch id by a multiple of
// 8, so the per-slice (id&7) phase is preserved.
__device__ __forceinline__ int xcd_swz(int orig, int nwg) {
  int q = nwg >> 3;
  return (orig & 7) * q + (orig >> 3);
}

// ---------------------------------------------------------------- fused input prep
// ONE launch at t=0: all 6 weight transposes (fp32 [K][N] -> bf16 [N][K]) plus
// the x fp32->bf16 convert. (R5-measured version: 32x32 tiles.)

__global__ __launch_bounds__(256) void k_prep(const float* __restrict__ wte_w,
                                              const float* __restrict__ kq_w,
                                              const float* __restrict__ v_w,
                                              const float* __restrict__ ao_w,
                                              const float* __restrict__ fc_w,
                                              const float* __restrict__ proj_w,
                                              const float* __restrict__ x,
                                              __hip_bfloat16* __restrict__ wT,
                                              __hip_bfloat16* __restrict__ x_bf) {
  const int bid = blockIdx.x;
  const float* in; __hip_bfloat16* out; int K, N, local;
  if (bid < 512)        { in = wte_w;  out = wT;           K = IN_DIM;  N = D_MODEL;     local = bid;        }
  else if (bid < 2560)  { in = kq_w;   out = wT +  524288; K = D_MODEL; N = 2 * D_MODEL; local = bid - 512;  }
  else if (bid < 3584)  { in = v_w;    out = wT + 2621440; K = D_MODEL; N = D_MODEL;     local = bid - 2560; }
  else if (bid < 4608)  { in = ao_w;   out = wT + 3670016; K = D_MODEL; N = D_MODEL;     local = bid - 3584; }
  else if (bid < 8704)  { in = fc_w;   out = wT + 4718592; K = D_MODEL; N = MLP_HID;     local = bid - 4608; }
  else if (bid < 10752) { in = proj_w; out = wT + 8912896; K = MLP_HID; N = IN_DIM;      local = bid - 8704; }
  else {  // convert x: 2048 blocks x 256 float4
    int i = (bid - 10752) * 256 + threadIdx.x;
    float4 v = ((const float4*)x)[i];
    short4v o;
    ((__hip_bfloat16*)&o)[0] = __float2bfloat16(v.x);
    ((__hip_bfloat16*)&o)[1] = __float2bfloat16(v.y);
    ((__hip_bfloat16*)&o)[2] = __float2bfloat16(v.z);
    ((__hip_bfloat16*)&o)[3] = __float2bfloat16(v.w);
    ((short4v*)x_bf)[i] = o;
    return;
  }
  __shared__ float tile[32][33];
  const int ntx = N >> 5;
  const int bx = local % ntx, by = local / ntx;
  const int n0 = bx * 32, k0 = by * 32;
  const int tx = threadIdx.x & 31, ty = threadIdx.x >> 5;  // ty in [0,8)
#pragma unroll
  for (int i = 0; i < 32; i += 8)
    tile[ty + i][tx] = in[(size_t)(k0 + ty + i) * N + n0 + tx];
  __syncthreads();
#pragma unroll
  for (int i = 0; i < 32; i += 8)
    out[(size_t)(n0 + ty + i) * K + k0 + tx] = __float2bfloat16(tile[tx][ty + i]);
}

// out0 = bias + sum of 8 split-K bf16 partials (8 outputs/thread, short8 loads)
__global__ __launch_bounds__(256) void k_reduce_proj(const __hip_bfloat16* __restrict__ part,
                                                     const float* __restrict__ bias,
                                                     float* __restrict__ out) {
  int i = blockIdx.x * 256 + threadIdx.x;          // over M_TOTAL*IN_DIM/8
  const size_t SP8 = (size_t)M_TOTAL * IN_DIM / 8; // short8 groups per split
  int cb = (i & (IN_DIM / 8 - 1)) * 2;             // float4 index of bias
  float4 s0 = ((const float4*)bias)[cb];
  float4 s1 = ((const float4*)bias)[cb + 1];
#pragma unroll
  for (int j = 0; j < 8; j++) {
    short8 v = ((const short8*)part)[i + j * SP8];
    s0.x += __bfloat162float(((const __hip_bfloat16*)&v)[0]);
    s0.y += __bfloat162float(((const __hip_bfloat16*)&v)[1]);
    s0.z += __bfloat162float(((const __hip_bfloat16*)&v)[2]);
    s0.w += __bfloat162float(((const __hip_bfloat16*)&v)[3]);
    s1.x += __bfloat162float(((const __hip_bfloat16*)&v)[4]);
    s1.y += __bfloat162float(((const __hip_bfloat16*)&v)[5]);
    s1.z += __bfloat162float(((const __hip_bfloat16*)&v)[6]);
    s1.w += __bfloat162float(((const __hip_bfloat16*)&v)[7]);
  }
  ((float4*)out)[i * 2]     = s0;
  ((float4*)out)[i * 2 + 1] = s1;
}

// ---------------------------------------------------------------- fused combine + layernorm

// hn = LN(part0 + part1 + wte_b + wpe[l])   -- embed combine fused, no h buffer
__global__ __launch_bounds__(256) void k_ln1_combine(const float* __restrict__ part,
                                                     const float* __restrict__ wb,
                                                     const float* __restrict__ wpe,
                                                     const float* __restrict__ lw,
                                                     const float* __restrict__ lb,
                                                     __hip_bfloat16* __restrict__ out_bf) {
  int row = blockIdx.x;
  int l = row & (SEQ_LEN - 1);
  float4 a = ((const float4*)(part + (size_t)row * D_MODEL))[threadIdx.x];
  float4 c = ((const float4*)(part + (size_t)(M_TOTAL + row) * D_MODEL))[threadIdx.x];
  float4 wb4 = ((const float4*)wb)[threadIdx.x];
  float4 pe4 = ((const float4*)(wpe + (size_t)l * D_MODEL))[threadIdx.x];
  float4 v;
  v.x = a.x + c.x + wb4.x + pe4.x;
  v.y = a.y + c.y + wb4.y + pe4.y;
  v.z = a.z + c.z + wb4.z + pe4.z;
  v.w = a.w + c.w + wb4.w + pe4.w;
  float s  = v.x + v.y + v.z + v.w;
  float sq = v.x * v.x + v.y * v.y + v.z * v.z + v.w * v.w;
#pragma unroll
  for (int o = 1; o < 64; o <<= 1) { s += __shfl_xor(s, o); sq += __shfl_xor(sq, o); }
  __shared__ float ss[4], ssq[4];
  int lane = threadIdx.x & 63, wv = threadIdx.x >> 6;
  if (lane == 0) { ss[wv] = s; ssq[wv] = sq; }
  __syncthreads();
  s  = ss[0] + ss[1] + ss[2] + ss[3];
  sq = ssq[0] + ssq[1] + ssq[2] + ssq[3];
  float mu  = s * (1.f / D_MODEL);
  float var = sq * (1.f / D_MODEL) - mu * mu;
  float rs  = rsqrtf(var + 1e-5f);
  float4 lw4 = ((const float4*)lw)[threadIdx.x];
  float4 lb4 = ((const float4*)lb)[threadIdx.x];
  size_t base = (size_t)row * D_MODEL + threadIdx.x * 4;
  out_bf[base + 0] = __float2bfloat16((v.x - mu) * rs * lw4.x + lb4.x);
  out_bf[base + 1] = __float2bfloat16((v.y - mu) * rs * lw4.y + lb4.y);
  out_bf[base + 2] = __float2bfloat16((v.z - mu) * rs * lw4.z + lb4.z);
  out_bf[base + 3] = __float2bfloat16((v.w - mu) * rs * lw4.w + lb4.w);
}

// attn_out = part0 + part1 + ao_b + hn (fp32, to d_out); xo = LN(attn_out)
__global__ __launch_bounds__(256) void k_ln2_combine(const float* __restrict__ part,
                                                     const float* __restrict__ bias,
                                                     const __hip_bfloat16* __restrict__ hn,
                                                     const float* __restrict__ lw,
                                                     const float* __restrict__ lb,
                                                     float* __restrict__ attn_out,
                                                     __hip_bfloat16* __restrict__ out_bf) {
  int row = blockIdx.x;
  float4 a = ((const float4*)(part + (size_t)row * D_MODEL))[threadIdx.x];
  float4 c = ((const float4*)(part + (size_t)(M_TOTAL + row) * D_MODEL))[threadIdx.x];
  float4 b4 = ((const float4*)bias)[threadIdx.x];
  short4v h4 = ((const short4v*)(hn + (size_t)row * D_MODEL))[threadIdx.x];
  float4 v;
  v.x = a.x + c.x + b4.x + __bfloat162float(((const __hip_bfloat16*)&h4)[0]);
  v.y = a.y + c.y + b4.y + __bfloat162float(((const __hip_bfloat16*)&h4)[1]);
  v.z = a.z + c.z + b4.z + __bfloat162float(((const __hip_bfloat16*)&h4)[2]);
  v.w = a.w + c.w + b4.w + __bfloat162float(((const __hip_bfloat16*)&h4)[3]);
  ((float4*)(attn_out + (size_t)row * D_MODEL))[threadIdx.x] = v;
  float s  = v.x + v.y + v.z + v.w;
  float sq = v.x * v.x + v.y * v.y + v.z * v.z + v.w * v.w;
#pragma unroll
  for (int o = 1; o < 64; o <<= 1) { s += __shfl_xor(s, o); sq += __shfl_xor(sq, o); }
  __shared__ float ss[4], ssq[4];
  int lane = threadIdx.x & 63, wv = threadIdx.x >> 6;
  if (lane == 0) { ss[wv] = s; ssq[wv] = sq; }
  __syncthreads();
  s  = ss[0] + ss[1] + ss[2] + ss[3];
  sq = ssq[0] + ssq[1] + ssq[2] + ssq[3];
  float mu  = s * (1.f / D_MODEL);
  float var = sq * (1.f / D_MODEL) - mu * mu;
  float rs  = rsqrtf(var + 1e-5f);
  float4 lw4 = ((const float4*)lw)[threadIdx.x];
  float4 lb4 = ((const float4*)lb)[threadIdx.x];
  size_t base = (size_t)row * D_MODEL + threadIdx.x * 4;
  out_bf[base + 0] = __float2bfloat16((v.x - mu) * rs * lw4.x + lb4.x);
  out_bf[base + 1] = __float2bfloat16((v.y - mu) * rs * lw4.y + lb4.y);
  out_bf[base + 2] = __float2bfloat16((v.z - mu) * rs * lw4.z + lb4.z);
  out_bf[base + 3] = __float2bfloat16((v.w - mu) * rs * lw4.w + lb4.w);
}

// ---------------------------------------------------------------- epilogues
// Fragment-granular: operator()(row, col, acc) handles rows row..row+3 at col.

struct KQVEpi {  // col<1024->k, <2048->q (prescaled), <3072->V^T (direct [b,h,d,l])
  const float* kq_b; const float* v_b;
  __hip_bfloat16* kb; __hip_bfloat16* qb; __hip_bfloat16* vt;
  __device__ void operator()(int row, int col, const floatx4& v) const {
    int b = row >> 11, l = row & (SEQ_LEN - 1);
    int which = col >> 10, c = col & (D_MODEL - 1);
    int head = c >> 6, d = c & 63;
    if (which == 2) {
      float bias = v_b[c];
      short4v o;
#pragma unroll
      for (int t = 0; t < 4; t++)
        ((__hip_bfloat16*)&o)[t] = __float2bfloat16(v[t] + bias);
      // 4 consecutive l at fixed d -> one 8B store in V^T layout
      *(short4v*)(vt + ((size_t)(b * N_HEAD + head) * HEAD_DIM + d) * SEQ_LEN + l) = o;
    } else {
      float bias = kq_b[col];
      float scale = (which == 1) ? 0.125f : 1.f;
      __hip_bfloat16* dst = (which == 0) ? kb : qb;
#pragma unroll
      for (int t = 0; t < 4; t++)
        dst[((size_t)(b * N_HEAD + head) * SEQ_LEN + l + t) * HEAD_DIM + d] =
            __float2bfloat16((v[t] + bias) * scale);
    }
  }
};

struct FCEpi {  // act = gelu_exact(acc + fc_b)  (bf16 out)
  const float* bias; __hip_bfloat16* act;
  __device__ void operator()(int row, int col, const floatx4& v) const {
    float bi = bias[col];
#pragma unroll
    for (int t = 0; t < 4; t++) {
      float x = v[t] + bi;
      float g = 0.5f * x * (1.f + erff(x * 0.70710678118654752f));
      act[(size_t)(row + t) * MLP_HID + col] = __float2bfloat16(g);
    }
  }
};

struct PartEpi {  // split-K fp32 partial store (N = D_MODEL)
  float* part;
  __device__ void operator()(int row, int col, const floatx4& v) const {
    float* p = part + (size_t)blockIdx.z * ((size_t)M_TOTAL * D_MODEL) +
               (size_t)row * D_MODEL + col;
#pragma unroll
    for (int t = 0; t < 4; t++) p[(size_t)t * D_MODEL] = v[t];
  }
};

struct PartBf16Epi {  // split-K bf16 partial store (N = IN_DIM)
  __hip_bfloat16* part;
  __device__ void operator()(int row, int col, const floatx4& v) const {
    __hip_bfloat16* p = part + (size_t)blockIdx.z * ((size_t)M_TOTAL * IN_DIM) +
                        (size_t)row * IN_DIM + col;
#pragma unroll
    for (int t = 0; t < 4; t++) p[(size_t)t * IN_DIM] = __float2bfloat16(v[t]);
  }
};

// ---------------------------------------------------------------- GEMM 128x128
// C[M,N] = A[M,K] @ B[K,N], A row-major bf16, B given as B^T [N][K] bf16.
// 128x128 tile, BK=64 (32 KB LDS), 256 threads = 4 waves (2x2), wave does
// 64x64 via 4x4 mfma_f32_16x16x32_bf16 frags. XOR-swizzled staging via
// global_load_lds. ~3 blocks/CU; cross-block wave overlap hides barrier drains.
// XCD-swizzled tile assignment (T1). Used for embed/kqv/ao.

template <class Epi>
__global__ __launch_bounds__(256) void k_gemm(const __hip_bfloat16* __restrict__ A,
                                              const __hip_bfloat16* __restrict__ Bt,
                                              int M, int N, int K, int Kchunk, Epi epi) {
  __shared__ __align__(16) short As[128 * 64];
  __shared__ __align__(16) short Bs[128 * 64];
  const int tid  = threadIdx.x;
  const int lane = tid & 63;
  const int w    = tid >> 6;
  const int wm   = (w >> 1) << 6;
  const int wn   = (w & 1) << 6;
  const int r    = lane & 15;
  const int quad = lane >> 4;
  const int swz = xcd_swz(blockIdx.y * gridDim.x + blockIdx.x, gridDim.x * gridDim.y);
  const int m0 = (swz / gridDim.x) << 7;
  const int n0 = (swz % gridDim.x) << 7;
  const int koff = blockIdx.z * Kchunk;

  const __hip_bfloat16* pa[4];
  const __hip_bfloat16* pb[4];
#pragma unroll
  for (int j = 0; j < 4; j++) {
    int s = tid + j * 256;
    int row = s >> 3;
    int c = (s & 7) ^ (row & 7);
    pa[j] = A  + (size_t)(m0 + row) * K + (c << 3) + koff;
    pb[j] = Bt + (size_t)(n0 + row) * K + (c << 3) + koff;
  }

  floatx4 acc[4][4];
#pragma unroll
  for (int i = 0; i < 4; i++)
#pragma unroll
    for (int j = 0; j < 4; j++) acc[i][j] = (floatx4){0.f, 0.f, 0.f, 0.f};

  int aoff[2][4], boff[2][4];
#pragma unroll
  for (int kk = 0; kk < 2; kk++)
#pragma unroll
    for (int i = 0; i < 4; i++) {
      int pc = ((quad + (kk << 2)) ^ (r & 7)) << 3;
      aoff[kk][i] = (wm + i * 16 + r) * 64 + pc;
      boff[kk][i] = (wn + i * 16 + r) * 64 + pc;
    }

  for (int k0 = 0; k0 < Kchunk; k0 += 64) {
    __syncthreads();
#pragma unroll
    for (int j = 0; j < 4; j++) {
      async_copy16(pa[j] + k0, &As[(tid + j * 256) * 8]);
      async_copy16(pb[j] + k0, &Bs[(tid + j * 256) * 8]);
    }
    __syncthreads();
#pragma unroll
    for (int kk = 0; kk < 2; kk++) {
      short8 fa[4], fb[4];
#pragma unroll
      for (int i = 0; i < 4; i++) {
        fa[i] = *(const short8*)&As[aoff[kk][i]];
        fb[i] = *(const short8*)&Bs[boff[kk][i]];
      }
#pragma unroll
      for (int i = 0; i < 4; i++)
#pragma unroll
        for (int j = 0; j < 4; j++)
          acc[i][j] = __builtin_amdgcn_mfma_f32_16x16x32_bf16(fa[i], fb[j], acc[i][j], 0, 0, 0);
    }
  }

#pragma unroll
  for (int i = 0; i < 4; i++)
#pragma unroll
    for (int j = 0; j < 4; j++)
      epi(m0 + wm + i * 16 + quad * 4, n0 + wn + j * 16 + r, acc[i][j]);
}

template <class Epi>
static void launch_gemm(const __hip_bfloat16* A, const __hip_bfloat16* Bt,
                        int M, int N, int K, Epi epi, hipStream_t s) {
  dim3 grid(N / 128, M / 128, 1);
  k_gemm<Epi><<<grid, 256, 0, s>>>(A, Bt, M, N, K, K, epi);
}

// ---------------------------------------------------------------- GEMM 256x256 (8-phase)
// Used for FC + proj. Register-pinned: VGPR 120 + 128 AGPR acc = 248/256.
// XCD-swizzled tile assignment (T1).

#define STAGE_A(BUF, H, KT)                                                       \
  do {                                                                            \
    async_copy16(ga + (size_t)((H) * 128) * K + (KT) * 64,                        \
                 &As[BUF][(tid + (H) * 1024) * 8]);                               \
    async_copy16(ga + (size_t)((H) * 128 + 64) * K + (KT) * 64,                   \
                 &As[BUF][(tid + (H) * 1024 + 512) * 8]);                         \
  } while (0)

#define STAGE_B(BUF, H, KT)                                                       \
  do {                                                                            \
    async_copy16(gb + (size_t)((H) * 128) * K + (KT) * 64,                        \
                 &Bs[BUF][(tid + (H) * 1024) * 8]);                               \
    async_copy16(gb + (size_t)((H) * 128 + 64) * K + (KT) * 64,                   \
                 &Bs[BUF][(tid + (H) * 1024 + 512) * 8]);                         \
  } while (0)

#define MFMA_BLK(IO, JO, BFX)                                                     \
  _Pragma("unroll") for (int i = 0; i < 4; i++) {                                 \
    _Pragma("unroll") for (int j = 0; j < 2; j++) {                               \
      acc[(IO) + i][(JO) + j] = __builtin_amdgcn_mfma_f32_16x16x32_bf16(          \
          af[i][0], BFX[j][0], acc[(IO) + i][(JO) + j], 0, 0, 0);                 \
      acc[(IO) + i][(JO) + j] = __builtin_amdgcn_mfma_f32_16x16x32_bf16(          \
          af[i][1], BFX[j][1], acc[(IO) + i][(JO) + j], 0, 0, 0);                 \
    }                                                                             \
  }

#define GTILE(T, BUF)                                                             \
  {                                                                               \
    _Pragma("unroll") for (int i = 0; i < 4; i++) {                               \
      af[i][0] = *(const short8*)&As[BUF][arb[i] + pc0];                          \
      af[i][1] = *(const short8*)&As[BUF][arb[i] + pc1];                          \
    }                                                                             \
    _Pragma("unroll") for (int j = 0; j < 2; j++) {                               \
      bf0[j][0] = *(const short8*)&Bs[BUF][brb[j] + pc0];                         \
      bf0[j][1] = *(const short8*)&Bs[BUF][brb[j] + pc1];                         \
    }                                                                             \
    if ((T) + 1 < nt) { STAGE_A((BUF) ^ 1, 1, (T) + 1); }                         \
    __builtin_amdgcn_s_barrier();                                                 \
    asm volatile("s_waitcnt lgkmcnt(0)" ::: "memory");                            \
    __builtin_amdgcn_s_setprio(1);                                                \
    MFMA_BLK(0, 0, bf0)                                                           \
    __builtin_amdgcn_s_setprio(0);                                                \
    __builtin_amdgcn_s_barrier();                                                 \
    _Pragma("unroll") for (int j = 0; j < 2; j++) {                               \
      bf1[j][0] = *(const short8*)&Bs[BUF][brb[j] + 8192 + pc0];                  \
      bf1[j][1] = *(const short8*)&Bs[BUF][brb[j] + 8192 + pc1];                  \
    }                                                                             \
    if ((T) + 2 < nt) { STAGE_A(BUF, 0, (T) + 2); }                               \
    __builtin_amdgcn_s_barrier();                                                 \
    asm volatile("s_waitcnt lgkmcnt(0)" ::: "memory");                            \
    __builtin_amdgcn_s_setprio(1);                                                \
    MFMA_BLK(0, 2, bf1)                                                           \
    __builtin_amdgcn_s_setprio(0);                                                \
    __builtin_amdgcn_s_barrier();                                                 \
    _Pragma("unroll") for (int i = 0; i < 4; i++) {                               \
      af[i][0] = *(const short8*)&As[BUF][arb[i] + 8192 + pc0];                   \
      af[i][1] = *(const short8*)&As[BUF][arb[i] + 8192 + pc1];                   \
    }                                                                             \
    if ((T) + 2 < nt) { STAGE_B(BUF, 0, (T) + 2); }                               \
    __builtin_amdgcn_s_barrier();                                                 \
    asm volatile("s_waitcnt lgkmcnt(0)" ::: "memory");                            \
    __builtin_amdgcn_s_setprio(1);                                                \
    MFMA_BLK(4, 0, bf0)                                                           \
    __builtin_amdgcn_s_setprio(0);                                                \
    __builtin_amdgcn_s_barrier();                                                 \
    if ((T) + 2 < nt) { STAGE_B(BUF, 1, (T) + 2); }                               \
    __builtin_amdgcn_s_setprio(1);                                                \
    MFMA_BLK(4, 2, bf1)                                                           \
    __builtin_amdgcn_s_setprio(0);                                                \
    if ((T) + 2 < nt) {                                                           \
      asm volatile("s_waitcnt vmcnt(6)" ::: "memory");                            \
    } else {                                                                      \
      asm volatile("s_waitcnt vmcnt(0)" ::: "memory");                            \
    }                                                                             \
    __builtin_amdgcn_s_barrier();                                                 \
  }

template <class Epi>
__global__ __launch_bounds__(512, 2) void k_gemm256(const __hip_bfloat16* __restrict__ A,
                                                    const __hip_bfloat16* __restrict__ Bt,
                                                    int M, int N, int K, int Kchunk, Epi epi) {
  (void)M; (void)N;
  __shared__ __align__(16) short As[2][16384];   // 2 x 32 KB
  __shared__ __align__(16) short Bs[2][16384];   // 2 x 32 KB
  const int tid  = threadIdx.x;
  const int lane = tid & 63;
  const int w    = tid >> 6;        // 0..7
  const int wr   = w >> 2;          // 0..1
  const int wc   = w & 3;           // 0..3
  const int r    = lane & 15;
  const int quad = lane >> 4;
  const int swz = xcd_swz(blockIdx.y * gridDim.x + blockIdx.x, gridDim.x * gridDim.y);
  const int m0 = (swz / gridDim.x) << 8;
  const int n0 = (swz % gridDim.x) << 8;
  const int koff = blockIdx.z * Kchunk;
  const int nt = Kchunk >> 6;       // K-tiles; must be even

  const int sr = tid >> 3;                     // 0..63
  const int sc = (tid & 7) ^ (sr & 7);
  const __hip_bfloat16* ga = A  + (size_t)(m0 + sr) * K + sc * 8 + koff;
  const __hip_bfloat16* gb = Bt + (size_t)(n0 + sr) * K + sc * 8 + koff;

  const int pc0 = ((quad    ) ^ (r & 7)) << 3;
  const int pc1 = ((quad + 4) ^ (r & 7)) << 3;
  int arb[4], brb[2];
#pragma unroll
  for (int i = 0; i < 4; i++) arb[i] = ((2 * i + wr) * 16 + r) * 64;
#pragma unroll
  for (int j = 0; j < 2; j++) brb[j] = ((4 * j + wc) * 16 + r) * 64;

  floatx4 acc[8][4];
#pragma unroll
  for (int i = 0; i < 8; i++)
#pragma unroll
    for (int j = 0; j < 4; j++) acc[i][j] = (floatx4){0.f, 0.f, 0.f, 0.f};
  short8 af[4][2], bf0[2][2], bf1[2][2];

  STAGE_A(0, 0, 0);
  STAGE_B(0, 0, 0);
  STAGE_B(0, 1, 0);
  STAGE_A(0, 1, 0);
  if (nt > 1) {
    STAGE_A(1, 0, 1);
    STAGE_B(1, 0, 1);
    STAGE_B(1, 1, 1);
    asm volatile("s_waitcnt vmcnt(6)" ::: "memory");
  } else {
    asm volatile("s_waitcnt vmcnt(0)" ::: "memory");
  }
  __builtin_amdgcn_s_barrier();

  for (int t = 0; t < nt; t += 2) {
    GTILE(t, 0)
    GTILE(t + 1, 1)
  }

#pragma unroll
  for (int i = 0; i < 8; i++)
#pragma unroll
    for (int j = 0; j < 4; j++)
      epi(m0 + (2 * i + wr) * 16 + quad * 4, n0 + (4 * j + wc) * 16 + r, acc[i][j]);
}

// ---------------------------------------------------------------- flash attention
// v4: 256 threads = 4 waves, wave owns 16 q-rows, block = 64 q-rows ->
// 1024 blocks (32 strips x 32 bh): fine-grained longest-first packing +
// ~3 blocks/CU resident (LDS 41 KB) for cross-block overlap; barriers sync
// only 4 waves. Double-buffered K/V via global_load_lds; counted vmcnt(4)
// pipeline, never drains to 0 mid-loop. Odd ktiles via guarded second ATILE.
// XOR-swizzle; S^T = K Q^T, p=exp(s) (scores bounded), deferred l; P^T via
// per-wave LDS; O^T += V^T P^T.

#define PSTR 68   // bf16 elems per q-row in P buffer

#define STAGE_KV(T, P)                                                         \
  do {                                                                         \
    async_copy16(kp + (size_t)((((T) << 6)) + row0) * HEAD_DIM + g0 * 8,       \
                 &Ks[P][c0 * 8]);                                              \
    async_copy16(kp + (size_t)((((T) << 6)) + row1) * HEAD_DIM + g1 * 8,       \
                 &Ks[P][c1 * 8]);                                              \
    async_copy16(vp + (size_t)row0 * SEQ_LEN + ((T) << 6) + g0 * 8,            \
                 &Vs[P][c0 * 8]);                                              \
    async_copy16(vp + (size_t)row1 * SEQ_LEN + ((T) << 6) + g1 * 8,            \
                 &Vs[P][c1 * 8]);                                              \
  } while (0)

#define QKSUB(KT, P)                                                           \
  {                                                                            \
    const int tss = ts + ((KT) << 4);                                          \
    short4v pk0;                                                               \
    if (tss < qend) {                                                          \
      const int krow = ((KT) << 4) + r;                                        \
      short8 a0 = *(const short8*)&Ks[P][(krow * 8 + (quad ^ sw)) * 8];        \
      short8 a1 = *(const short8*)&Ks[P][(krow * 8 + ((quad ^ sw) ^ 4)) * 8];  \
      floatx4 s0 = (floatx4){0.f, 0.f, 0.f, 0.f};                              \
      s0 = __builtin_amdgcn_mfma_f32_16x16x32_bf16(a0, qf0, s0, 0, 0, 0);      \
      s0 = __builtin_amdgcn_mfma_f32_16x16x32_bf16(a1, qf1, s0, 0, 0, 0);      \
      if (tss + 15 > qbw) {                                                    \
        int off0 = qbw + r - tss;                                              \
        _Pragma("unroll") for (int tt = 0; tt < 4; tt++) {                     \
          int kl = (quad << 2) + tt;                                           \
          if (kl > off0) s0[tt] = -INFINITY;                                   \
        }                                                                      \
      }                                                                        \
      _Pragma("unroll") for (int tt = 0; tt < 4; tt++) {                       \
        float e0 = __expf(s0[tt]); ls0 += e0;                                  \
        ((__hip_bfloat16*)&pk0)[tt] = __float2bfloat16(e0);                    \
      }                                                                        \
    } else {                                                                   \
      pk0 = (short4v){0, 0, 0, 0};                                             \
    }                                                                          \
    *(short4v*)(pw + r * PSTR + ((KT) << 4) + (quad << 2)) = pk0;              \
  }

#define ATILE(T, P)                                                            \
  {                                                                            \
    const int ts = (T) << 6;                                                   \
    QKSUB(0, P)                                                                \
    QKSUB(1, P)                                                                \
    QKSUB(2, P)                                                                \
    QKSUB(3, P)                                                                \
    __builtin_amdgcn_s_setprio(1);                                             \
    _Pragma("unroll") for (int c = 0; c < 2; c++) {                            \
      short8 pb0 = *(const short8*)(pw + r * PSTR + (c << 5) + (quad << 3));   \
      _Pragma("unroll") for (int fd = 0; fd < 4; fd++) {                       \
        const int vrow = (fd << 4) + r;                                        \
        short8 va = *(const short8*)&Vs[P][(vrow * 8 + (((c << 2) + quad) ^ sw)) * 8]; \
        of[fd] = __builtin_amdgcn_mfma_f32_16x16x32_bf16(va, pb0, of[fd], 0, 0, 0); \
      }                                                                        \
    }                                                                          \
    __builtin_amdgcn_s_setprio(0);                                             \
    __builtin_amdgcn_s_barrier();                                              \
    if ((T) + 2 < ktiles) {                                                    \
      STAGE_KV((T) + 2, P);                                                    \
      asm volatile("s_waitcnt vmcnt(4)" ::: "memory");                         \
    } else {                                                                   \
      asm volatile("s_waitcnt vmcnt(0)" ::: "memory");                         \
    }                                                                          \
    __builtin_amdgcn_s_barrier();                                              \
    __builtin_amdgcn_sched_barrier(0);                                         \
  }

__global__ __launch_bounds__(256, 3) void k_flash_attn(const __hip_bfloat16* __restrict__ kb,
                                                       const __hip_bfloat16* __restrict__ qb,
                                                       const __hip_bfloat16* __restrict__ vtb,
                                                       __hip_bfloat16* __restrict__ ob) {
  __shared__ __align__(16) short Ks[2][64 * 64];         // 16 KB
  __shared__ __align__(16) short Vs[2][64 * 64];         // 16 KB
  __shared__ __align__(16) __hip_bfloat16 Pb[4][16 * PSTR];  // 8.5 KB
  const int tid  = threadIdx.x;
  const int lane = tid & 63;
  const int w    = tid >> 6;                         // 0..3
  const int r    = lane & 15;
  const int quad = lane >> 4;
  const int sw   = r & 7;
  const int bh    = blockIdx.x & 31;                 // 32 (b,h)
  const int strip = (SEQ_LEN / 64 - 1) - (blockIdx.x >> 5);  // longest first
  const int qb0   = strip << 6;                      // block q start (64 rows)
  const int qbw   = qb0 + (w << 4);                  // wave q start (16 rows)
  const int qend  = qbw + 16;
  const int b = bh >> 4, h = bh & (N_HEAD - 1);

  const __hip_bfloat16* qp = qb  + ((size_t)bh * SEQ_LEN + qbw) * HEAD_DIM;
  const __hip_bfloat16* kp = kb  + (size_t)bh * SEQ_LEN * HEAD_DIM;
  const __hip_bfloat16* vp = vtb + (size_t)bh * HEAD_DIM * SEQ_LEN;  // [d][l]
  __hip_bfloat16* pw = &Pb[w][0];

  short8 qf0 = *(const short8*)(qp + r * HEAD_DIM + quad * 8);
  short8 qf1 = *(const short8*)(qp + r * HEAD_DIM + quad * 8 + 32);

  floatx4 of[4];
#pragma unroll
  for (int i = 0; i < 4; i++) of[i] = (floatx4){0.f, 0.f, 0.f, 0.f};
  float ls0 = 0.f;

  // staging: thread tid stages chunks tid and tid+256 of each 64x64 tile
  const int c0 = tid, c1 = tid + 256;
  const int row0 = c0 >> 3, g0 = (c0 & 7) ^ (row0 & 7);
  const int row1 = c1 >> 3, g1 = (c1 & 7) ^ (row1 & 7);

  const int ktiles = strip + 1;   // may be odd
  STAGE_KV(0, 0);
  if (ktiles > 1) {
    STAGE_KV(1, 1);
    asm volatile("s_waitcnt vmcnt(4)" ::: "memory");
  } else {
    asm volatile("s_waitcnt vmcnt(0)" ::: "memory");
  }
  __builtin_amdgcn_s_barrier();
  __builtin_amdgcn_sched_barrier(0);

  for (int t = 0; t < ktiles; t += 2) {
    ATILE(t, 0)
    if (t + 1 < ktiles) { ATILE(t + 1, 1) }
  }

  ls0 += __shfl_xor(ls0, 16); ls0 += __shfl_xor(ls0, 32);
  float inv0 = 1.f / ls0;

  size_t orow = ((size_t)b * SEQ_LEN + qbw + r) * D_MODEL + (size_t)h * HEAD_DIM;
#pragma unroll
  for (int fd = 0; fd < 4; fd++) {
    short4v o4;
#pragma unroll
    for (int tt = 0; tt < 4; tt++)
      ((__hip_bfloat16*)&o4)[tt] = __float2bfloat16(of[fd][tt] * inv0);
    *(short4v*)(ob + orow + fd * 16 + quad * 4) = o4;
  }
}

// ---------------------------------------------------------------- driver

extern "C" void kernel_launch(void* const* d_in, const int* in_sizes, int n_in,
                              void* d_out, int out_size, void* d_ws, size_t ws_size,
                              hipStream_t stream) {
  (void)in_sizes; (void)n_in; (void)out_size; (void)ws_size;
  const float* x      = (const float*)d_in[0];
  const float* wte_w  = (const float*)d_in[1];
  const float* wte_b  = (const float*)d_in[2];
  const float* wpe    = (const float*)d_in[3];
  const float* ln1_w  = (const float*)d_in[4];
  const float* ln1_b  = (const float*)d_in[5];
  const float* kq_w   = (const float*)d_in[6];
  const float* kq_b   = (const float*)d_in[7];
  const float* v_w    = (const float*)d_in[8];
  const float* v_b    = (const float*)d_in[9];
  const float* ao_w   = (const float*)d_in[10];
  const float* ao_b   = (const float*)d_in[11];
  const float* ln2_w  = (const float*)d_in[12];
  const float* ln2_b  = (const float*)d_in[13];
  const float* fc_w   = (const float*)d_in[14];
  const float* fc_b   = (const float*)d_in[15];
  const float* proj_w = (const float*)d_in[16];
  const float* proj_b = (const float*)d_in[17];

  float* out0     = (float*)d_out;                                  // (B,L,512)
  float* attn_out = out0 + (size_t)M_TOTAL * IN_DIM;                // (B,L,1024)

  char* ws = (char*)d_ws;
  // layout (MB): wT_all [0,22) | x_bf [22,26) | R1 [26,58) | k [58,66) |
  //              q [66,74) | vt [74,82) | o [82,90) | hn [90,98)
  __hip_bfloat16* wT    = (__hip_bfloat16*)ws;
  __hip_bfloat16* x_bf  = (__hip_bfloat16*)(ws + 22 * 1048576);
  char* R1              = ws + 26 * 1048576;                         // embed_part / ao_part / act
  float* embed_part     = (float*)R1;
  float* ao_part        = (float*)R1;
  __hip_bfloat16* act   = (__hip_bfloat16*)R1;
  __hip_bfloat16* k_bf  = (__hip_bfloat16*)(ws + 58 * 1048576);
  __hip_bfloat16* q_bf  = (__hip_bfloat16*)(ws + 66 * 1048576);
  __hip_bfloat16* vt_bf = (__hip_bfloat16*)(ws + 74 * 1048576);
  __hip_bfloat16* o_bf  = (__hip_bfloat16*)(ws + 82 * 1048576);
  __hip_bfloat16* hn_bf = (__hip_bfloat16*)(ws + 90 * 1048576);
  __hip_bfloat16* xo_bf = k_bf;                                      // k dead after attn
  __hip_bfloat16* proj_part = k_bf;                                  // 32 MB over k/q/vt/o (dead at step 9)

  // wT sub-offsets (bf16 elements)
  __hip_bfloat16* wteT  = wT;            // [512][1024]^T  -> [1024][512]
  __hip_bfloat16* kqvT  = wT +  524288;  // kq^T [2048][1024] then v^T [1024][1024] (contiguous)
  __hip_bfloat16* aoT   = wT + 3670016;
  __hip_bfloat16* fcT   = wT + 4718592;
  __hip_bfloat16* projT = wT + 8912896;

  // 1. fused prep: all 6 weight transposes + x convert (inputs only)
  k_prep<<<12800, 256, 0, stream>>>(wte_w, kq_w, v_w, ao_w, fc_w, proj_w, x, wT, x_bf);

  // 2. embed GEMM: split-K x2 fp32 partials
  {
    dim3 grid(D_MODEL / 128, M_TOTAL / 128, 2);
    k_gemm<PartEpi><<<grid, 256, 0, stream>>>(x_bf, wteT, M_TOTAL, D_MODEL, IN_DIM, IN_DIM / 2,
                                              PartEpi{embed_part});
  }

  // 3. hn = LN1(part0 + part1 + wte_b + wpe)
  k_ln1_combine<<<M_TOTAL, 256, 0, stream>>>(embed_part, wte_b, wpe, ln1_w, ln1_b, hn_bf);

  // 4. fused kqv = hn @ [kq_w | v_w]  (N=3072, 768 blocks); V^T written directly
  launch_gemm(hn_bf, kqvT, M_TOTAL, 3 * D_MODEL, D_MODEL,
              KQVEpi{kq_b, v_b, k_bf, q_bf, vt_bf}, stream);

  // 5. flash attention -> o  [b,l,h*d] bf16  (64-row blocks, 1024 blocks)
  k_flash_attn<<<(SEQ_LEN / 64) * 32, 256, 0, stream>>>(k_bf, q_bf, vt_bf, o_bf);

  // 6. ao GEMM: split-K x2 fp32 partials
  {
    dim3 grid(D_MODEL / 128, M_TOTAL / 128, 2);
    k_gemm<PartEpi><<<grid, 256, 0, stream>>>(o_bf, aoT, M_TOTAL, D_MODEL, D_MODEL, D_MODEL / 2,
                                              PartEpi{ao_part});
  }

  // 7. attn_out = part0+part1+ao_b+hn (to d_out); xo = LN2(attn_out)
  k_ln2_combine<<<M_TOTAL, 256, 0, stream>>>(ao_part, ao_b, hn_bf, ln2_w, ln2_b, attn_out, xo_bf);

  // 8. act = gelu(xo @ fc_w + fc_b)   (256^2 8-phase, 256 blocks, nt=16)
  {
    dim3 grid(MLP_HID / 256, M_TOTAL / 256, 1);
    k_gemm256<FCEpi><<<grid, 512, 0, stream>>>(xo_bf, fcT, M_TOTAL, MLP_HID, D_MODEL, D_MODEL,
                                               FCEpi{fc_b, act});
  }

  // 9. out = act @ proj_w + proj_b  (256^2 8-phase, split-K x8 bf16 partials; nt=8)
  {
    dim3 grid(IN_DIM / 256, M_TOTAL / 256, 8);
    k_gemm256<PartBf16Epi><<<grid, 512, 0, stream>>>(act, projT, M_TOTAL, IN_DIM, MLP_HID,
                                                     MLP_HID / 8, PartBf16Epi{proj_part});
  }
  k_reduce_proj<<<M_TOTAL * IN_DIM / 8 / 256, 256, 0, stream>>>(proj_part, proj_b, out0);
}

// Round 9
// 357.672 us; speedup vs baseline: 1.0018x; 1.0018x over previous
//
#include <hip/hip_runtime.h>
#include <hip/hip_bf16.h>
#include <cmath>

#define D_MODEL   1024
#define N_HEAD    16
#define HEAD_DIM  64
#define SEQ_LEN   2048
#define NBATCH    2
#define M_TOTAL   (NBATCH * SEQ_LEN)   // 4096
#define IN_DIM    512
#define MLP_HID   4096

typedef __attribute__((ext_vector_type(8))) short short8;
typedef __attribute__((ext_vector_type(4))) short short4v;
typedef __attribute__((ext_vector_type(4))) float floatx4;

typedef const __attribute__((address_space(1))) void* gas_ptr;
typedef __attribute__((address_space(3))) void* las_ptr;

__device__ __forceinline__ void async_copy16(const void* g, void* l) {
  __builtin_amdgcn_global_load_lds((gas_ptr)g, (las_ptr)l, 16, 0, 0);
}

// ---------------------------------------------------------------- fused input prep
// ONE launch at t=0: all 6 weight transposes (fp32 [K][N] -> bf16 [N][K]) plus
// the x fp32->bf16 convert. (R5-measured version: 32x32 tiles.)

__global__ __launch_bounds__(256) void k_prep(const float* __restrict__ wte_w,
                                              const float* __restrict__ kq_w,
                                              const float* __restrict__ v_w,
                                              const float* __restrict__ ao_w,
                                              const float* __restrict__ fc_w,
                                              const float* __restrict__ proj_w,
                                              const float* __restrict__ x,
                                              __hip_bfloat16* __restrict__ wT,
                                              __hip_bfloat16* __restrict__ x_bf) {
  const int bid = blockIdx.x;
  const float* in; __hip_bfloat16* out; int K, N, local;
  if (bid < 512)        { in = wte_w;  out = wT;           K = IN_DIM;  N = D_MODEL;     local = bid;        }
  else if (bid < 2560)  { in = kq_w;   out = wT +  524288; K = D_MODEL; N = 2 * D_MODEL; local = bid - 512;  }
  else if (bid < 3584)  { in = v_w;    out = wT + 2621440; K = D_MODEL; N = D_MODEL;     local = bid - 2560; }
  else if (bid < 4608)  { in = ao_w;   out = wT + 3670016; K = D_MODEL; N = D_MODEL;     local = bid - 3584; }
  else if (bid < 8704)  { in = fc_w;   out = wT + 4718592; K = D_MODEL; N = MLP_HID;     local = bid - 4608; }
  else if (bid < 10752) { in = proj_w; out = wT + 8912896; K = MLP_HID; N = IN_DIM;      local = bid - 8704; }
  else {  // convert x: 2048 blocks x 256 float4
    int i = (bid - 10752) * 256 + threadIdx.x;
    float4 v = ((const float4*)x)[i];
    short4v o;
    ((__hip_bfloat16*)&o)[0] = __float2bfloat16(v.x);
    ((__hip_bfloat16*)&o)[1] = __float2bfloat16(v.y);
    ((__hip_bfloat16*)&o)[2] = __float2bfloat16(v.z);
    ((__hip_bfloat16*)&o)[3] = __float2bfloat16(v.w);
    ((short4v*)x_bf)[i] = o;
    return;
  }
  __shared__ float tile[32][33];
  const int ntx = N >> 5;
  const int bx = local % ntx, by = local / ntx;
  const int n0 = bx * 32, k0 = by * 32;
  const int tx = threadIdx.x & 31, ty = threadIdx.x >> 5;  // ty in [0,8)
#pragma unroll
  for (int i = 0; i < 32; i += 8)
    tile[ty + i][tx] = in[(size_t)(k0 + ty + i) * N + n0 + tx];
  __syncthreads();
#pragma unroll
  for (int i = 0; i < 32; i += 8)
    out[(size_t)(n0 + ty + i) * K + k0 + tx] = __float2bfloat16(tile[tx][ty + i]);
}

// out0 = bias + sum of 8 split-K bf16 partials (8 outputs/thread, short8 loads)
__global__ __launch_bounds__(256) void k_reduce_proj(const __hip_bfloat16* __restrict__ part,
                                                     const float* __restrict__ bias,
                                                     float* __restrict__ out) {
  int i = blockIdx.x * 256 + threadIdx.x;          // over M_TOTAL*IN_DIM/8
  const size_t SP8 = (size_t)M_TOTAL * IN_DIM / 8; // short8 groups per split
  int cb = (i & (IN_DIM / 8 - 1)) * 2;             // float4 index of bias
  float4 s0 = ((const float4*)bias)[cb];
  float4 s1 = ((const float4*)bias)[cb + 1];
#pragma unroll
  for (int j = 0; j < 8; j++) {
    short8 v = ((const short8*)part)[i + j * SP8];
    s0.x += __bfloat162float(((const __hip_bfloat16*)&v)[0]);
    s0.y += __bfloat162float(((const __hip_bfloat16*)&v)[1]);
    s0.z += __bfloat162float(((const __hip_bfloat16*)&v)[2]);
    s0.w += __bfloat162float(((const __hip_bfloat16*)&v)[3]);
    s1.x += __bfloat162float(((const __hip_bfloat16*)&v)[4]);
    s1.y += __bfloat162float(((const __hip_bfloat16*)&v)[5]);
    s1.z += __bfloat162float(((const __hip_bfloat16*)&v)[6]);
    s1.w += __bfloat162float(((const __hip_bfloat16*)&v)[7]);
  }
  ((float4*)out)[i * 2]     = s0;
  ((float4*)out)[i * 2 + 1] = s1;
}

// ---------------------------------------------------------------- fused combine + layernorm

// hn = LN(part0 + part1 + wte_b + wpe[l])   -- embed combine fused, no h buffer
__global__ __launch_bounds__(256) void k_ln1_combine(const float* __restrict__ part,
                                                     const float* __restrict__ wb,
                                                     const float* __restrict__ wpe,
                                                     const float* __restrict__ lw,
                                                     const float* __restrict__ lb,
                                                     __hip_bfloat16* __restrict__ out_bf) {
  int row = blockIdx.x;
  int l = row & (SEQ_LEN - 1);
  float4 a = ((const float4*)(part + (size_t)row * D_MODEL))[threadIdx.x];
  float4 c = ((const float4*)(part + (size_t)(M_TOTAL + row) * D_MODEL))[threadIdx.x];
  float4 wb4 = ((const float4*)wb)[threadIdx.x];
  float4 pe4 = ((const float4*)(wpe + (size_t)l * D_MODEL))[threadIdx.x];
  float4 v;
  v.x = a.x + c.x + wb4.x + pe4.x;
  v.y = a.y + c.y + wb4.y + pe4.y;
  v.z = a.z + c.z + wb4.z + pe4.z;
  v.w = a.w + c.w + wb4.w + pe4.w;
  float s  = v.x + v.y + v.z + v.w;
  float sq = v.x * v.x + v.y * v.y + v.z * v.z + v.w * v.w;
#pragma unroll
  for (int o = 1; o < 64; o <<= 1) { s += __shfl_xor(s, o); sq += __shfl_xor(sq, o); }
  __shared__ float ss[4], ssq[4];
  int lane = threadIdx.x & 63, wv = threadIdx.x >> 6;
  if (lane == 0) { ss[wv] = s; ssq[wv] = sq; }
  __syncthreads();
  s  = ss[0] + ss[1] + ss[2] + ss[3];
  sq = ssq[0] + ssq[1] + ssq[2] + ssq[3];
  float mu  = s * (1.f / D_MODEL);
  float var = sq * (1.f / D_MODEL) - mu * mu;
  float rs  = rsqrtf(var + 1e-5f);
  float4 lw4 = ((const float4*)lw)[threadIdx.x];
  float4 lb4 = ((const float4*)lb)[threadIdx.x];
  size_t base = (size_t)row * D_MODEL + threadIdx.x * 4;
  out_bf[base + 0] = __float2bfloat16((v.x - mu) * rs * lw4.x + lb4.x);
  out_bf[base + 1] = __float2bfloat16((v.y - mu) * rs * lw4.y + lb4.y);
  out_bf[base + 2] = __float2bfloat16((v.z - mu) * rs * lw4.z + lb4.z);
  out_bf[base + 3] = __float2bfloat16((v.w - mu) * rs * lw4.w + lb4.w);
}

// attn_out = part0 + part1 + ao_b + hn (fp32, to d_out); xo = LN(attn_out)
__global__ __launch_bounds__(256) void k_ln2_combine(const float* __restrict__ part,
                                                     const float* __restrict__ bias,
                                                     const __hip_bfloat16* __restrict__ hn,
                                                     const float* __restrict__ lw,
                                                     const float* __restrict__ lb,
                                                     float* __restrict__ attn_out,
                                                     __hip_bfloat16* __restrict__ out_bf) {
  int row = blockIdx.x;
  float4 a = ((const float4*)(part + (size_t)row * D_MODEL))[threadIdx.x];
  float4 c = ((const float4*)(part + (size_t)(M_TOTAL + row) * D_MODEL))[threadIdx.x];
  float4 b4 = ((const float4*)bias)[threadIdx.x];
  short4v h4 = ((const short4v*)(hn + (size_t)row * D_MODEL))[threadIdx.x];
  float4 v;
  v.x = a.x + c.x + b4.x + __bfloat162float(((const __hip_bfloat16*)&h4)[0]);
  v.y = a.y + c.y + b4.y + __bfloat162float(((const __hip_bfloat16*)&h4)[1]);
  v.z = a.z + c.z + b4.z + __bfloat162float(((const __hip_bfloat16*)&h4)[2]);
  v.w = a.w + c.w + b4.w + __bfloat162float(((const __hip_bfloat16*)&h4)[3]);
  ((float4*)(attn_out + (size_t)row * D_MODEL))[threadIdx.x] = v;
  float s  = v.x + v.y + v.z + v.w;
  float sq = v.x * v.x + v.y * v.y + v.z * v.z + v.w * v.w;
#pragma unroll
  for (int o = 1; o < 64; o <<= 1) { s += __shfl_xor(s, o); sq += __shfl_xor(sq, o); }
  __shared__ float ss[4], ssq[4];
  int lane = threadIdx.x & 63, wv = threadIdx.x >> 6;
  if (lane == 0) { ss[wv] = s; ssq[wv] = sq; }
  __syncthreads();
  s  = ss[0] + ss[1] + ss[2] + ss[3];
  sq = ssq[0] + ssq[1] + ssq[2] + ssq[3];
  float mu  = s * (1.f / D_MODEL);
  float var = sq * (1.f / D_MODEL) - mu * mu;
  float rs  = rsqrtf(var + 1e-5f);
  float4 lw4 = ((const float4*)lw)[threadIdx.x];
  float4 lb4 = ((const float4*)lb)[threadIdx.x];
  size_t base = (size_t)row * D_MODEL + threadIdx.x * 4;
  out_bf[base + 0] = __float2bfloat16((v.x - mu) * rs * lw4.x + lb4.x);
  out_bf[base + 1] = __float2bfloat16((v.y - mu) * rs * lw4.y + lb4.y);
  out_bf[base + 2] = __float2bfloat16((v.z - mu) * rs * lw4.z + lb4.z);
  out_bf[base + 3] = __float2bfloat16((v.w - mu) * rs * lw4.w + lb4.w);
}

// ---------------------------------------------------------------- epilogues
// Fragment-granular: operator()(row, col, acc) handles rows row..row+3 at col.

struct KQVEpi {  // col<1024->k, <2048->q (prescaled), <3072->V^T (direct [b,h,d,l])
  const float* kq_b; const float* v_b;
  __hip_bfloat16* kb; __hip_bfloat16* qb; __hip_bfloat16* vt;
  __device__ void operator()(int row, int col, const floatx4& v) const {
    int b = row >> 11, l = row & (SEQ_LEN - 1);
    int which = col >> 10, c = col & (D_MODEL - 1);
    int head = c >> 6, d = c & 63;
    if (which == 2) {
      float bias = v_b[c];
      short4v o;
#pragma unroll
      for (int t = 0; t < 4; t++)
        ((__hip_bfloat16*)&o)[t] = __float2bfloat16(v[t] + bias);
      // 4 consecutive l at fixed d -> one 8B store in V^T layout
      *(short4v*)(vt + ((size_t)(b * N_HEAD + head) * HEAD_DIM + d) * SEQ_LEN + l) = o;
    } else {
      float bias = kq_b[col];
      float scale = (which == 1) ? 0.125f : 1.f;
      __hip_bfloat16* dst = (which == 0) ? kb : qb;
#pragma unroll
      for (int t = 0; t < 4; t++)
        dst[((size_t)(b * N_HEAD + head) * SEQ_LEN + l + t) * HEAD_DIM + d] =
            __float2bfloat16((v[t] + bias) * scale);
    }
  }
};

// gelu_exact via Abramowitz-Stegun 7.1.26 erf (|eps| <= 1.5e-7 absolute --
// ~3 orders below bf16 rounding). Branchless (copysign), ~15 VALU ops vs
// ocml erff's ~35+ with divergent range handling. Epilogue VALU was ~35%
// of the FC dispatch (R8 counters).
__device__ __forceinline__ float fast_gelu(float x) {
  float ax = fabsf(x) * 0.70710678118654752f;
  float t  = 1.f / (1.f + 0.3275911f * ax);
  float p  = ((((1.061405429f * t - 1.453152027f) * t + 1.421413741f) * t
               - 0.284496736f) * t + 0.254829592f) * t;
  float e  = __expf(-ax * ax);
  float er = 1.f - p * e;                    // erf(|x|/sqrt2)
  return 0.5f * x * (1.f + copysignf(er, x));
}

struct FCEpi {  // act = gelu(acc + fc_b)  (bf16 out)
  const float* bias; __hip_bfloat16* act;
  __device__ void operator()(int row, int col, const floatx4& v) const {
    float bi = bias[col];
#pragma unroll
    for (int t = 0; t < 4; t++) {
      float g = fast_gelu(v[t] + bi);
      act[(size_t)(row + t) * MLP_HID + col] = __float2bfloat16(g);
    }
  }
};

struct PartEpi {  // split-K fp32 partial store (N = D_MODEL)
  float* part;
  __device__ void operator()(int row, int col, const floatx4& v) const {
    float* p = part + (size_t)blockIdx.z * ((size_t)M_TOTAL * D_MODEL) +
               (size_t)row * D_MODEL + col;
#pragma unroll
    for (int t = 0; t < 4; t++) p[(size_t)t * D_MODEL] = v[t];
  }
};

struct PartBf16Epi {  // split-K bf16 partial store (N = IN_DIM)
  __hip_bfloat16* part;
  __device__ void operator()(int row, int col, const floatx4& v) const {
    __hip_bfloat16* p = part + (size_t)blockIdx.z * ((size_t)M_TOTAL * IN_DIM) +
                        (size_t)row * IN_DIM + col;
#pragma unroll
    for (int t = 0; t < 4; t++) p[(size_t)t * IN_DIM] = __float2bfloat16(v[t]);
  }
};

// ---------------------------------------------------------------- GEMM 128x128
// C[M,N] = A[M,K] @ B[K,N], A row-major bf16, B given as B^T [N][K] bf16.
// 128x128 tile, BK=64 (32 KB LDS), 256 threads = 4 waves (2x2), wave does
// 64x64 via 4x4 mfma_f32_16x16x32_bf16 frags. XOR-swizzled staging via
// global_load_lds. ~3 blocks/CU; cross-block wave overlap hides barrier drains.
// Used for embed/kqv/ao. (XCD swizzle tried R8: FETCH unchanged, net regression
// -- reverted.)

template <class Epi>
__global__ __launch_bounds__(256) void k_gemm(const __hip_bfloat16* __restrict__ A,
                                              const __hip_bfloat16* __restrict__ Bt,
                                              int M, int N, int K, int Kchunk, Epi epi) {
  __shared__ __align__(16) short As[128 * 64];
  __shared__ __align__(16) short Bs[128 * 64];
  const int tid  = threadIdx.x;
  const int lane = tid & 63;
  const int w    = tid >> 6;
  const int wm   = (w >> 1) << 6;
  const int wn   = (w & 1) << 6;
  const int r    = lane & 15;
  const int quad = lane >> 4;
  const int m0 = blockIdx.y << 7;
  const int n0 = blockIdx.x << 7;
  const int koff = blockIdx.z * Kchunk;

  const __hip_bfloat16* pa[4];
  const __hip_bfloat16* pb[4];
#pragma unroll
  for (int j = 0; j < 4; j++) {
    int s = tid + j * 256;
    int row = s >> 3;
    int c = (s & 7) ^ (row & 7);
    pa[j] = A  + (size_t)(m0 + row) * K + (c << 3) + koff;
    pb[j] = Bt + (size_t)(n0 + row) * K + (c << 3) + koff;
  }

  floatx4 acc[4][4];
#pragma unroll
  for (int i = 0; i < 4; i++)
#pragma unroll
    for (int j = 0; j < 4; j++) acc[i][j] = (floatx4){0.f, 0.f, 0.f, 0.f};

  int aoff[2][4], boff[2][4];
#pragma unroll
  for (int kk = 0; kk < 2; kk++)
#pragma unroll
    for (int i = 0; i < 4; i++) {
      int pc = ((quad + (kk << 2)) ^ (r & 7)) << 3;
      aoff[kk][i] = (wm + i * 16 + r) * 64 + pc;
      boff[kk][i] = (wn + i * 16 + r) * 64 + pc;
    }

  for (int k0 = 0; k0 < Kchunk; k0 += 64) {
    __syncthreads();
#pragma unroll
    for (int j = 0; j < 4; j++) {
      async_copy16(pa[j] + k0, &As[(tid + j * 256) * 8]);
      async_copy16(pb[j] + k0, &Bs[(tid + j * 256) * 8]);
    }
    __syncthreads();
#pragma unroll
    for (int kk = 0; kk < 2; kk++) {
      short8 fa[4], fb[4];
#pragma unroll
      for (int i = 0; i < 4; i++) {
        fa[i] = *(const short8*)&As[aoff[kk][i]];
        fb[i] = *(const short8*)&Bs[boff[kk][i]];
      }
#pragma unroll
      for (int i = 0; i < 4; i++)
#pragma unroll
        for (int j = 0; j < 4; j++)
          acc[i][j] = __builtin_amdgcn_mfma_f32_16x16x32_bf16(fa[i], fb[j], acc[i][j], 0, 0, 0);
    }
  }

#pragma unroll
  for (int i = 0; i < 4; i++)
#pragma unroll
    for (int j = 0; j < 4; j++)
      epi(m0 + wm + i * 16 + quad * 4, n0 + wn + j * 16 + r, acc[i][j]);
}

template <class Epi>
static void launch_gemm(const __hip_bfloat16* A, const __hip_bfloat16* Bt,
                        int M, int N, int K, Epi epi, hipStream_t s) {
  dim3 grid(N / 128, M / 128, 1);
  k_gemm<Epi><<<grid, 256, 0, s>>>(A, Bt, M, N, K, K, epi);
}

// ---------------------------------------------------------------- GEMM 256x256 (8-phase)
// Used for FC + proj. Register-pinned: VGPR 120 + 128 AGPR acc = 248/256.

#define STAGE_A(BUF, H, KT)                                                       \
  do {                                                                            \
    async_copy16(ga + (size_t)((H) * 128) * K + (KT) * 64,                        \
                 &As[BUF][(tid + (H) * 1024) * 8]);                               \
    async_copy16(ga + (size_t)((H) * 128 + 64) * K + (KT) * 64,                   \
                 &As[BUF][(tid + (H) * 1024 + 512) * 8]);                         \
  } while (0)

#define STAGE_B(BUF, H, KT)                                                       \
  do {                                                                            \
    async_copy16(gb + (size_t)((H) * 128) * K + (KT) * 64,                        \
                 &Bs[BUF][(tid + (H) * 1024) * 8]);                               \
    async_copy16(gb + (size_t)((H) * 128 + 64) * K + (KT) * 64,                   \
                 &Bs[BUF][(tid + (H) * 1024 + 512) * 8]);                         \
  } while (0)

#define MFMA_BLK(IO, JO, BFX)                                                     \
  _Pragma("unroll") for (int i = 0; i < 4; i++) {                                 \
    _Pragma("unroll") for (int j = 0; j < 2; j++) {                               \
      acc[(IO) + i][(JO) + j] = __builtin_amdgcn_mfma_f32_16x16x32_bf16(          \
          af[i][0], BFX[j][0], acc[(IO) + i][(JO) + j], 0, 0, 0);                 \
      acc[(IO) + i][(JO) + j] = __builtin_amdgcn_mfma_f32_16x16x32_bf16(          \
          af[i][1], BFX[j][1], acc[(IO) + i][(JO) + j], 0, 0, 0);                 \
    }                                                                             \
  }

#define GTILE(T, BUF)                                                             \
  {                                                                               \
    _Pragma("unroll") for (int i = 0; i < 4; i++) {                               \
      af[i][0] = *(const short8*)&As[BUF][arb[i] + pc0];                          \
      af[i][1] = *(const short8*)&As[BUF][arb[i] + pc1];                          \
    }                                                                             \
    _Pragma("unroll") for (int j = 0; j < 2; j++) {                               \
      bf0[j][0] = *(const short8*)&Bs[BUF][brb[j] + pc0];                         \
      bf0[j][1] = *(const short8*)&Bs[BUF][brb[j] + pc1];                         \
    }                                                                             \
    if ((T) + 1 < nt) { STAGE_A((BUF) ^ 1, 1, (T) + 1); }                         \
    __builtin_amdgcn_s_barrier();                                                 \
    asm volatile("s_waitcnt lgkmcnt(0)" ::: "memory");                            \
    __builtin_amdgcn_s_setprio(1);                                                \
    MFMA_BLK(0, 0, bf0)                                                           \
    __builtin_amdgcn_s_setprio(0);                                                \
    __builtin_amdgcn_s_barrier();                                                 \
    _Pragma("unroll") for (int j = 0; j < 2; j++) {                               \
      bf1[j][0] = *(const short8*)&Bs[BUF][brb[j] + 8192 + pc0];                  \
      bf1[j][1] = *(const short8*)&Bs[BUF][brb[j] + 8192 + pc1];                  \
    }                                                                             \
    if ((T) + 2 < nt) { STAGE_A(BUF, 0, (T) + 2); }                               \
    __builtin_amdgcn_s_barrier();                                                 \
    asm volatile("s_waitcnt lgkmcnt(0)" ::: "memory");                            \
    __builtin_amdgcn_s_setprio(1);                                                \
    MFMA_BLK(0, 2, bf1)                                                           \
    __builtin_amdgcn_s_setprio(0);                                                \
    __builtin_amdgcn_s_barrier();                                                 \
    _Pragma("unroll") for (int i = 0; i < 4; i++) {                               \
      af[i][0] = *(const short8*)&As[BUF][arb[i] + 8192 + pc0];                   \
      af[i][1] = *(const short8*)&As[BUF][arb[i] + 8192 + pc1];                   \
    }                                                                             \
    if ((T) + 2 < nt) { STAGE_B(BUF, 0, (T) + 2); }                               \
    __builtin_amdgcn_s_barrier();                                                 \
    asm volatile("s_waitcnt lgkmcnt(0)" ::: "memory");                            \
    __builtin_amdgcn_s_setprio(1);                                                \
    MFMA_BLK(4, 0, bf0)                                                           \
    __builtin_amdgcn_s_setprio(0);                                                \
    __builtin_amdgcn_s_barrier();                                                 \
    if ((T) + 2 < nt) { STAGE_B(BUF, 1, (T) + 2); }                               \
    __builtin_amdgcn_s_setprio(1);                                                \
    MFMA_BLK(4, 2, bf1)                                                           \
    __builtin_amdgcn_s_setprio(0);                                                \
    if ((T) + 2 < nt) {                                                           \
      asm volatile("s_waitcnt vmcnt(6)" ::: "memory");                            \
    } else {                                                                      \
      asm volatile("s_waitcnt vmcnt(0)" ::: "memory");                            \
    }                                                                             \
    __builtin_amdgcn_s_barrier();                                                 \
  }

template <class Epi>
__global__ __launch_bounds__(512, 2) void k_gemm256(const __hip_bfloat16* __restrict__ A,
                                                    const __hip_bfloat16* __restrict__ Bt,
                                                    int M, int N, int K, int Kchunk, Epi epi) {
  (void)M; (void)N;
  __shared__ __align__(16) short As[2][16384];   // 2 x 32 KB
  __shared__ __align__(16) short Bs[2][16384];   // 2 x 32 KB
  const int tid  = threadIdx.x;
  const int lane = tid & 63;
  const int w    = tid >> 6;        // 0..7
  const int wr   = w >> 2;          // 0..1
  const int wc   = w & 3;           // 0..3
  const int r    = lane & 15;
  const int quad = lane >> 4;
  const int m0 = blockIdx.y << 8;
  const int n0 = blockIdx.x << 8;
  const int koff = blockIdx.z * Kchunk;
  const int nt = Kchunk >> 6;       // K-tiles; must be even

  const int sr = tid >> 3;                     // 0..63
  const int sc = (tid & 7) ^ (sr & 7);
  const __hip_bfloat16* ga = A  + (size_t)(m0 + sr) * K + sc * 8 + koff;
  const __hip_bfloat16* gb = Bt + (size_t)(n0 + sr) * K + sc * 8 + koff;

  const int pc0 = ((quad    ) ^ (r & 7)) << 3;
  const int pc1 = ((quad + 4) ^ (r & 7)) << 3;
  int arb[4], brb[2];
#pragma unroll
  for (int i = 0; i < 4; i++) arb[i] = ((2 * i + wr) * 16 + r) * 64;
#pragma unroll
  for (int j = 0; j < 2; j++) brb[j] = ((4 * j + wc) * 16 + r) * 64;

  floatx4 acc[8][4];
#pragma unroll
  for (int i = 0; i < 8; i++)
#pragma unroll
    for (int j = 0; j < 4; j++) acc[i][j] = (floatx4){0.f, 0.f, 0.f, 0.f};
  short8 af[4][2], bf0[2][2], bf1[2][2];

  STAGE_A(0, 0, 0);
  STAGE_B(0, 0, 0);
  STAGE_B(0, 1, 0);
  STAGE_A(0, 1, 0);
  if (nt > 1) {
    STAGE_A(1, 0, 1);
    STAGE_B(1, 0, 1);
    STAGE_B(1, 1, 1);
    asm volatile("s_waitcnt vmcnt(6)" ::: "memory");
  } else {
    asm volatile("s_waitcnt vmcnt(0)" ::: "memory");
  }
  __builtin_amdgcn_s_barrier();

  for (int t = 0; t < nt; t += 2) {
    GTILE(t, 0)
    GTILE(t + 1, 1)
  }

#pragma unroll
  for (int i = 0; i < 8; i++)
#pragma unroll
    for (int j = 0; j < 4; j++)
      epi(m0 + (2 * i + wr) * 16 + quad * 4, n0 + (4 * j + wc) * 16 + r, acc[i][j]);
}

// ---------------------------------------------------------------- flash attention
// v4: 256 threads = 4 waves, wave owns 16 q-rows, block = 64 q-rows ->
// 1024 blocks (32 strips x 32 bh): fine-grained longest-first packing +
// ~3 blocks/CU resident (LDS 41 KB) for cross-block overlap; barriers sync
// only 4 waves. Double-buffered K/V via global_load_lds; counted vmcnt(4)
// pipeline, never drains to 0 mid-loop. Odd ktiles via guarded second ATILE.
// XOR-swizzle; S^T = K Q^T, p=exp(s) (scores bounded), deferred l; P^T via
// per-wave LDS; O^T += V^T P^T.

#define PSTR 68   // bf16 elems per q-row in P buffer

#define STAGE_KV(T, P)                                                         \
  do {                                                                         \
    async_copy16(kp + (size_t)((((T) << 6)) + row0) * HEAD_DIM + g0 * 8,       \
                 &Ks[P][c0 * 8]);                                              \
    async_copy16(kp + (size_t)((((T) << 6)) + row1) * HEAD_DIM + g1 * 8,       \
                 &Ks[P][c1 * 8]);                                              \
    async_copy16(vp + (size_t)row0 * SEQ_LEN + ((T) << 6) + g0 * 8,            \
                 &Vs[P][c0 * 8]);                                              \
    async_copy16(vp + (size_t)row1 * SEQ_LEN + ((T) << 6) + g1 * 8,            \
                 &Vs[P][c1 * 8]);                                              \
  } while (0)

#define QKSUB(KT, P)                                                           \
  {                                                                            \
    const int tss = ts + ((KT) << 4);                                          \
    short4v pk0;                                                               \
    if (tss < qend) {                                                          \
      const int krow = ((KT) << 4) + r;                                        \
      short8 a0 = *(const short8*)&Ks[P][(krow * 8 + (quad ^ sw)) * 8];        \
      short8 a1 = *(const short8*)&Ks[P][(krow * 8 + ((quad ^ sw) ^ 4)) * 8];  \
      floatx4 s0 = (floatx4){0.f, 0.f, 0.f, 0.f};                              \
      s0 = __builtin_amdgcn_mfma_f32_16x16x32_bf16(a0, qf0, s0, 0, 0, 0);      \
      s0 = __builtin_amdgcn_mfma_f32_16x16x32_bf16(a1, qf1, s0, 0, 0, 0);      \
      if (tss + 15 > qbw) {                                                    \
        int off0 = qbw + r - tss;                                              \
        _Pragma("unroll") for (int tt = 0; tt < 4; tt++) {                     \
          int kl = (quad << 2) + tt;                                           \
          if (kl > off0) s0[tt] = -INFINITY;                                   \
        }                                                                      \
      }                                                                        \
      _Pragma("unroll") for (int tt = 0; tt < 4; tt++) {                       \
        float e0 = __expf(s0[tt]); ls0 += e0;                                  \
        ((__hip_bfloat16*)&pk0)[tt] = __float2bfloat16(e0);                    \
      }                                                                        \
    } else {                                                                   \
      pk0 = (short4v){0, 0, 0, 0};                                             \
    }                                                                          \
    *(short4v*)(pw + r * PSTR + ((KT) << 4) + (quad << 2)) = pk0;              \
  }

#define ATILE(T, P)                                                            \
  {                                                                            \
    const int ts = (T) << 6;                                                   \
    QKSUB(0, P)                                                                \
    QKSUB(1, P)                                                                \
    QKSUB(2, P)                                                                \
    QKSUB(3, P)                                                                \
    __builtin_amdgcn_s_setprio(1);                                             \
    _Pragma("unroll") for (int c = 0; c < 2; c++) {                            \
      short8 pb0 = *(const short8*)(pw + r * PSTR + (c << 5) + (quad << 3));   \
      _Pragma("unroll") for (int fd = 0; fd < 4; fd++) {                       \
        const int vrow = (fd << 4) + r;                                        \
        short8 va = *(const short8*)&Vs[P][(vrow * 8 + (((c << 2) + quad) ^ sw)) * 8]; \
        of[fd] = __builtin_amdgcn_mfma_f32_16x16x32_bf16(va, pb0, of[fd], 0, 0, 0); \
      }                                                                        \
    }                                                                          \
    __builtin_amdgcn_s_setprio(0);                                             \
    __builtin_amdgcn_s_barrier();                                              \
    if ((T) + 2 < ktiles) {                                                    \
      STAGE_KV((T) + 2, P);                                                    \
      asm volatile("s_waitcnt vmcnt(4)" ::: "memory");                         \
    } else {                                                                   \
      asm volatile("s_waitcnt vmcnt(0)" ::: "memory");                         \
    }                                                                          \
    __builtin_amdgcn_s_barrier();                                              \
    __builtin_amdgcn_sched_barrier(0);                                         \
  }

__global__ __launch_bounds__(256, 3) void k_flash_attn(const __hip_bfloat16* __restrict__ kb,
                                                       const __hip_bfloat16* __restrict__ qb,
                                                       const __hip_bfloat16* __restrict__ vtb,
                                                       __hip_bfloat16* __restrict__ ob) {
  __shared__ __align__(16) short Ks[2][64 * 64];         // 16 KB
  __shared__ __align__(16) short Vs[2][64 * 64];         // 16 KB
  __shared__ __align__(16) __hip_bfloat16 Pb[4][16 * PSTR];  // 8.5 KB
  const int tid  = threadIdx.x;
  const int lane = tid & 63;
  const int w    = tid >> 6;                         // 0..3
  const int r    = lane & 15;
  const int quad = lane >> 4;
  const int sw   = r & 7;
  const int bh    = blockIdx.x & 31;                 // 32 (b,h)
  const int strip = (SEQ_LEN / 64 - 1) - (blockIdx.x >> 5);  // longest first
  const int qb0   = strip << 6;                      // block q start (64 rows)
  const int qbw   = qb0 + (w << 4);                  // wave q start (16 rows)
  const int qend  = qbw + 16;
  const int b = bh >> 4, h = bh & (N_HEAD - 1);

  const __hip_bfloat16* qp = qb  + ((size_t)bh * SEQ_LEN + qbw) * HEAD_DIM;
  const __hip_bfloat16* kp = kb  + (size_t)bh * SEQ_LEN * HEAD_DIM;
  const __hip_bfloat16* vp = vtb + (size_t)bh * HEAD_DIM * SEQ_LEN;  // [d][l]
  __hip_bfloat16* pw = &Pb[w][0];

  short8 qf0 = *(const short8*)(qp + r * HEAD_DIM + quad * 8);
  short8 qf1 = *(const short8*)(qp + r * HEAD_DIM + quad * 8 + 32);

  floatx4 of[4];
#pragma unroll
  for (int i = 0; i < 4; i++) of[i] = (floatx4){0.f, 0.f, 0.f, 0.f};
  float ls0 = 0.f;

  // staging: thread tid stages chunks tid and tid+256 of each 64x64 tile
  const int c0 = tid, c1 = tid + 256;
  const int row0 = c0 >> 3, g0 = (c0 & 7) ^ (row0 & 7);
  const int row1 = c1 >> 3, g1 = (c1 & 7) ^ (row1 & 7);

  const int ktiles = strip + 1;   // may be odd
  STAGE_KV(0, 0);
  if (ktiles > 1) {
    STAGE_KV(1, 1);
    asm volatile("s_waitcnt vmcnt(4)" ::: "memory");
  } else {
    asm volatile("s_waitcnt vmcnt(0)" ::: "memory");
  }
  __builtin_amdgcn_s_barrier();
  __builtin_amdgcn_sched_barrier(0);

  for (int t = 0; t < ktiles; t += 2) {
    ATILE(t, 0)
    if (t + 1 < ktiles) { ATILE(t + 1, 1) }
  }

  ls0 += __shfl_xor(ls0, 16); ls0 += __shfl_xor(ls0, 32);
  float inv0 = 1.f / ls0;

  size_t orow = ((size_t)b * SEQ_LEN + qbw + r) * D_MODEL + (size_t)h * HEAD_DIM;
#pragma unroll
  for (int fd = 0; fd < 4; fd++) {
    short4v o4;
#pragma unroll
    for (int tt = 0; tt < 4; tt++)
      ((__hip_bfloat16*)&o4)[tt] = __float2bfloat16(of[fd][tt] * inv0);
    *(short4v*)(ob + orow + fd * 16 + quad * 4) = o4;
  }
}

// ---------------------------------------------------------------- driver

extern "C" void kernel_launch(void* const* d_in, const int* in_sizes, int n_in,
                              void* d_out, int out_size, void* d_ws, size_t ws_size,
                              hipStream_t stream) {
  (void)in_sizes; (void)n_in; (void)out_size; (void)ws_size;
  const float* x      = (const float*)d_in[0];
  const float* wte_w  = (const float*)d_in[1];
  const float* wte_b  = (const float*)d_in[2];
  const float* wpe    = (const float*)d_in[3];
  const float* ln1_w  = (const float*)d_in[4];
  const float* ln1_b  = (const float*)d_in[5];
  const float* kq_w   = (const float*)d_in[6];
  const float* kq_b   = (const float*)d_in[7];
  const float* v_w    = (const float*)d_in[8];
  const float* v_b    = (const float*)d_in[9];
  const float* ao_w   = (const float*)d_in[10];
  const float* ao_b   = (const float*)d_in[11];
  const float* ln2_w  = (const float*)d_in[12];
  const float* ln2_b  = (const float*)d_in[13];
  const float* fc_w   = (const float*)d_in[14];
  const float* fc_b   = (const float*)d_in[15];
  const float* proj_w = (const float*)d_in[16];
  const float* proj_b = (const float*)d_in[17];

  float* out0     = (float*)d_out;                                  // (B,L,512)
  float* attn_out = out0 + (size_t)M_TOTAL * IN_DIM;                // (B,L,1024)

  char* ws = (char*)d_ws;
  // layout (MB): wT_all [0,22) | x_bf [22,26) | R1 [26,58) | k [58,66) |
  //              q [66,74) | vt [74,82) | o [82,90) | hn [90,98)
  __hip_bfloat16* wT    = (__hip_bfloat16*)ws;
  __hip_bfloat16* x_bf  = (__hip_bfloat16*)(ws + 22 * 1048576);
  char* R1              = ws + 26 * 1048576;                         // embed_part / ao_part / act
  float* embed_part     = (float*)R1;
  float* ao_part        = (float*)R1;
  __hip_bfloat16* act   = (__hip_bfloat16*)R1;
  __hip_bfloat16* k_bf  = (__hip_bfloat16*)(ws + 58 * 1048576);
  __hip_bfloat16* q_bf  = (__hip_bfloat16*)(ws + 66 * 1048576);
  __hip_bfloat16* vt_bf = (__hip_bfloat16*)(ws + 74 * 1048576);
  __hip_bfloat16* o_bf  = (__hip_bfloat16*)(ws + 82 * 1048576);
  __hip_bfloat16* hn_bf = (__hip_bfloat16*)(ws + 90 * 1048576);
  __hip_bfloat16* xo_bf = k_bf;                                      // k dead after attn
  __hip_bfloat16* proj_part = k_bf;                                  // 32 MB over k/q/vt/o (dead at step 9)

  // wT sub-offsets (bf16 elements)
  __hip_bfloat16* wteT  = wT;            // [512][1024]^T  -> [1024][512]
  __hip_bfloat16* kqvT  = wT +  524288;  // kq^T [2048][1024] then v^T [1024][1024] (contiguous)
  __hip_bfloat16* aoT   = wT + 3670016;
  __hip_bfloat16* fcT   = wT + 4718592;
  __hip_bfloat16* projT = wT + 8912896;

  // 1. fused prep: all 6 weight transposes + x convert (inputs only)
  k_prep<<<12800, 256, 0, stream>>>(wte_w, kq_w, v_w, ao_w, fc_w, proj_w, x, wT, x_bf);

  // 2. embed GEMM: split-K x2 fp32 partials
  {
    dim3 grid(D_MODEL / 128, M_TOTAL / 128, 2);
    k_gemm<PartEpi><<<grid, 256, 0, stream>>>(x_bf, wteT, M_TOTAL, D_MODEL, IN_DIM, IN_DIM / 2,
                                              PartEpi{embed_part});
  }

  // 3. hn = LN1(part0 + part1 + wte_b + wpe)
  k_ln1_combine<<<M_TOTAL, 256, 0, stream>>>(embed_part, wte_b, wpe, ln1_w, ln1_b, hn_bf);

  // 4. fused kqv = hn @ [kq_w | v_w]  (N=3072, 768 blocks); V^T written directly
  launch_gemm(hn_bf, kqvT, M_TOTAL, 3 * D_MODEL, D_MODEL,
              KQVEpi{kq_b, v_b, k_bf, q_bf, vt_bf}, stream);

  // 5. flash attention -> o  [b,l,h*d] bf16  (64-row blocks, 1024 blocks)
  k_flash_attn<<<(SEQ_LEN / 64) * 32, 256, 0, stream>>>(k_bf, q_bf, vt_bf, o_bf);

  // 6. ao GEMM: split-K x2 fp32 partials
  {
    dim3 grid(D_MODEL / 128, M_TOTAL / 128, 2);
    k_gemm<PartEpi><<<grid, 256, 0, stream>>>(o_bf, aoT, M_TOTAL, D_MODEL, D_MODEL, D_MODEL / 2,
                                              PartEpi{ao_part});
  }

  // 7. attn_out = part0+part1+ao_b+hn (to d_out); xo = LN2(attn_out)
  k_ln2_combine<<<M_TOTAL, 256, 0, stream>>>(ao_part, ao_b, hn_bf, ln2_w, ln2_b, attn_out, xo_bf);

  // 8. act = gelu(xo @ fc_w + fc_b)   (256^2 8-phase, 256 blocks, nt=16)
  {
    dim3 grid(MLP_HID / 256, M_TOTAL / 256, 1);
    k_gemm256<FCEpi><<<grid, 512, 0, stream>>>(xo_bf, fcT, M_TOTAL, MLP_HID, D_MODEL, D_MODEL,
                                               FCEpi{fc_b, act});
  }

  // 9. out = act @ proj_w + proj_b  (256^2 8-phase, split-K x8 bf16 partials; nt=8)
  {
    dim3 grid(IN_DIM / 256, M_TOTAL / 256, 8);
    k_gemm256<PartBf16Epi><<<grid, 512, 0, stream>>>(act, projT, M_TOTAL, IN_DIM, MLP_HID,
                                                     MLP_HID / 8, PartBf16Epi{proj_part});
  }
  k_reduce_proj<<<M_TOTAL * IN_DIM / 8 / 256, 256, 0, stream>>>(proj_part, proj_b, out0);
}

// Round 10
// 349.395 us; speedup vs baseline: 1.0256x; 1.0237x over previous
//
#include <hip/hip_runtime.h>
#include <hip/hip_bf16.h>
#include <cmath>

#define D_MODEL   1024
#define N_HEAD    16
#define HEAD_DIM  64
#define SEQ_LEN   2048
#define NBATCH    2
#define M_TOTAL   (NBATCH * SEQ_LEN)   // 4096
#define IN_DIM    512
#define MLP_HID   4096

typedef __attribute__((ext_vector_type(8))) short short8;
typedef __attribute__((ext_vector_type(4))) short short4v;
typedef __attribute__((ext_vector_type(4))) float floatx4;

typedef const __attribute__((address_space(1))) void* gas_ptr;
typedef __attribute__((address_space(3))) void* las_ptr;

__device__ __forceinline__ void async_copy16(const void* g, void* l) {
  __builtin_amdgcn_global_load_lds((gas_ptr)g, (las_ptr)l, 16, 0, 0);
}

// ---------------------------------------------------------------- fused input prep
// ONE launch at t=0: all 6 weight transposes (fp32 [K][N] -> bf16 [N][K]) plus
// the x fp32->bf16 convert. 64x64 tiles, short8 coalesced stores (16B/lane,
// 128B runs -- the 32x32 version stored scalar bf16 in 64B runs, a G13
// violation on ~42MB of writes). Tile ranges: wte[0,128) kq[128,640)
// v[640,896) ao[896,1152) fc[1152,2176) proj[2176,2688) x[2688,4736).

__global__ __launch_bounds__(256) void k_prep(const float* __restrict__ wte_w,
                                              const float* __restrict__ kq_w,
                                              const float* __restrict__ v_w,
                                              const float* __restrict__ ao_w,
                                              const float* __restrict__ fc_w,
                                              const float* __restrict__ proj_w,
                                              const float* __restrict__ x,
                                              __hip_bfloat16* __restrict__ wT,
                                              __hip_bfloat16* __restrict__ x_bf) {
  const int bid = blockIdx.x;
  const float* in; __hip_bfloat16* out; int K, N, local;
  if (bid < 128)        { in = wte_w;  out = wT;           K = IN_DIM;  N = D_MODEL;     local = bid;        }
  else if (bid < 640)   { in = kq_w;   out = wT +  524288; K = D_MODEL; N = 2 * D_MODEL; local = bid - 128;  }
  else if (bid < 896)   { in = v_w;    out = wT + 2621440; K = D_MODEL; N = D_MODEL;     local = bid - 640;  }
  else if (bid < 1152)  { in = ao_w;   out = wT + 3670016; K = D_MODEL; N = D_MODEL;     local = bid - 896;  }
  else if (bid < 2176)  { in = fc_w;   out = wT + 4718592; K = D_MODEL; N = MLP_HID;     local = bid - 1152; }
  else if (bid < 2688)  { in = proj_w; out = wT + 8912896; K = MLP_HID; N = IN_DIM;      local = bid - 2176; }
  else {  // convert x: 2048 blocks x 256 float4
    int i = (bid - 2688) * 256 + threadIdx.x;
    float4 v = ((const float4*)x)[i];
    short4v o;
    ((__hip_bfloat16*)&o)[0] = __float2bfloat16(v.x);
    ((__hip_bfloat16*)&o)[1] = __float2bfloat16(v.y);
    ((__hip_bfloat16*)&o)[2] = __float2bfloat16(v.z);
    ((__hip_bfloat16*)&o)[3] = __float2bfloat16(v.w);
    ((short4v*)x_bf)[i] = o;
    return;
  }
  __shared__ __hip_bfloat16 t[64][73];
  const int ntx = N >> 6;
  const int n0 = (local % ntx) * 64, k0 = (local / ntx) * 64;
  const int tx = threadIdx.x & 7, ty = threadIdx.x >> 3;  // 8 x 32
#pragma unroll
  for (int i = 0; i < 64; i += 32) {
    const float* src = in + (size_t)(k0 + ty + i) * N + n0 + tx * 8;
    float4 v0 = ((const float4*)src)[0];
    float4 v1 = ((const float4*)src)[1];
    t[ty + i][tx * 8 + 0] = __float2bfloat16(v0.x);
    t[ty + i][tx * 8 + 1] = __float2bfloat16(v0.y);
    t[ty + i][tx * 8 + 2] = __float2bfloat16(v0.z);
    t[ty + i][tx * 8 + 3] = __float2bfloat16(v0.w);
    t[ty + i][tx * 8 + 4] = __float2bfloat16(v1.x);
    t[ty + i][tx * 8 + 5] = __float2bfloat16(v1.y);
    t[ty + i][tx * 8 + 6] = __float2bfloat16(v1.z);
    t[ty + i][tx * 8 + 7] = __float2bfloat16(v1.w);
  }
  __syncthreads();
#pragma unroll
  for (int i = 0; i < 64; i += 32) {
    int nr = ty + i;
    short8 o;
#pragma unroll
    for (int j = 0; j < 8; j++) ((__hip_bfloat16*)&o)[j] = t[tx * 8 + j][nr];
    *(short8*)(out + (size_t)(n0 + nr) * K + k0 + tx * 8) = o;
  }
}

// out0 = bias + sum of 8 split-K bf16 partials (8 outputs/thread, short8 loads)
__global__ __launch_bounds__(256) void k_reduce_proj(const __hip_bfloat16* __restrict__ part,
                                                     const float* __restrict__ bias,
                                                     float* __restrict__ out) {
  int i = blockIdx.x * 256 + threadIdx.x;          // over M_TOTAL*IN_DIM/8
  const size_t SP8 = (size_t)M_TOTAL * IN_DIM / 8; // short8 groups per split
  int cb = (i & (IN_DIM / 8 - 1)) * 2;             // float4 index of bias
  float4 s0 = ((const float4*)bias)[cb];
  float4 s1 = ((const float4*)bias)[cb + 1];
#pragma unroll
  for (int j = 0; j < 8; j++) {
    short8 v = ((const short8*)part)[i + j * SP8];
    s0.x += __bfloat162float(((const __hip_bfloat16*)&v)[0]);
    s0.y += __bfloat162float(((const __hip_bfloat16*)&v)[1]);
    s0.z += __bfloat162float(((const __hip_bfloat16*)&v)[2]);
    s0.w += __bfloat162float(((const __hip_bfloat16*)&v)[3]);
    s1.x += __bfloat162float(((const __hip_bfloat16*)&v)[4]);
    s1.y += __bfloat162float(((const __hip_bfloat16*)&v)[5]);
    s1.z += __bfloat162float(((const __hip_bfloat16*)&v)[6]);
    s1.w += __bfloat162float(((const __hip_bfloat16*)&v)[7]);
  }
  ((float4*)out)[i * 2]     = s0;
  ((float4*)out)[i * 2 + 1] = s1;
}

// ---------------------------------------------------------------- fused combine + layernorm

// hn = LN(part0 + part1 + wte_b + wpe[l])   -- embed combine fused, no h buffer
__global__ __launch_bounds__(256) void k_ln1_combine(const float* __restrict__ part,
                                                     const float* __restrict__ wb,
                                                     const float* __restrict__ wpe,
                                                     const float* __restrict__ lw,
                                                     const float* __restrict__ lb,
                                                     __hip_bfloat16* __restrict__ out_bf) {
  int row = blockIdx.x;
  int l = row & (SEQ_LEN - 1);
  float4 a = ((const float4*)(part + (size_t)row * D_MODEL))[threadIdx.x];
  float4 c = ((const float4*)(part + (size_t)(M_TOTAL + row) * D_MODEL))[threadIdx.x];
  float4 wb4 = ((const float4*)wb)[threadIdx.x];
  float4 pe4 = ((const float4*)(wpe + (size_t)l * D_MODEL))[threadIdx.x];
  float4 v;
  v.x = a.x + c.x + wb4.x + pe4.x;
  v.y = a.y + c.y + wb4.y + pe4.y;
  v.z = a.z + c.z + wb4.z + pe4.z;
  v.w = a.w + c.w + wb4.w + pe4.w;
  float s  = v.x + v.y + v.z + v.w;
  float sq = v.x * v.x + v.y * v.y + v.z * v.z + v.w * v.w;
#pragma unroll
  for (int o = 1; o < 64; o <<= 1) { s += __shfl_xor(s, o); sq += __shfl_xor(sq, o); }
  __shared__ float ss[4], ssq[4];
  int lane = threadIdx.x & 63, wv = threadIdx.x >> 6;
  if (lane == 0) { ss[wv] = s; ssq[wv] = sq; }
  __syncthreads();
  s  = ss[0] + ss[1] + ss[2] + ss[3];
  sq = ssq[0] + ssq[1] + ssq[2] + ssq[3];
  float mu  = s * (1.f / D_MODEL);
  float var = sq * (1.f / D_MODEL) - mu * mu;
  float rs  = rsqrtf(var + 1e-5f);
  float4 lw4 = ((const float4*)lw)[threadIdx.x];
  float4 lb4 = ((const float4*)lb)[threadIdx.x];
  size_t base = (size_t)row * D_MODEL + threadIdx.x * 4;
  out_bf[base + 0] = __float2bfloat16((v.x - mu) * rs * lw4.x + lb4.x);
  out_bf[base + 1] = __float2bfloat16((v.y - mu) * rs * lw4.y + lb4.y);
  out_bf[base + 2] = __float2bfloat16((v.z - mu) * rs * lw4.z + lb4.z);
  out_bf[base + 3] = __float2bfloat16((v.w - mu) * rs * lw4.w + lb4.w);
}

// attn_out = part0 + part1 + ao_b + hn (fp32, to d_out); xo = LN(attn_out)
__global__ __launch_bounds__(256) void k_ln2_combine(const float* __restrict__ part,
                                                     const float* __restrict__ bias,
                                                     const __hip_bfloat16* __restrict__ hn,
                                                     const float* __restrict__ lw,
                                                     const float* __restrict__ lb,
                                                     float* __restrict__ attn_out,
                                                     __hip_bfloat16* __restrict__ out_bf) {
  int row = blockIdx.x;
  float4 a = ((const float4*)(part + (size_t)row * D_MODEL))[threadIdx.x];
  float4 c = ((const float4*)(part + (size_t)(M_TOTAL + row) * D_MODEL))[threadIdx.x];
  float4 b4 = ((const float4*)bias)[threadIdx.x];
  short4v h4 = ((const short4v*)(hn + (size_t)row * D_MODEL))[threadIdx.x];
  float4 v;
  v.x = a.x + c.x + b4.x + __bfloat162float(((const __hip_bfloat16*)&h4)[0]);
  v.y = a.y + c.y + b4.y + __bfloat162float(((const __hip_bfloat16*)&h4)[1]);
  v.z = a.z + c.z + b4.z + __bfloat162float(((const __hip_bfloat16*)&h4)[2]);
  v.w = a.w + c.w + b4.w + __bfloat162float(((const __hip_bfloat16*)&h4)[3]);
  ((float4*)(attn_out + (size_t)row * D_MODEL))[threadIdx.x] = v;
  float s  = v.x + v.y + v.z + v.w;
  float sq = v.x * v.x + v.y * v.y + v.z * v.z + v.w * v.w;
#pragma unroll
  for (int o = 1; o < 64; o <<= 1) { s += __shfl_xor(s, o); sq += __shfl_xor(sq, o); }
  __shared__ float ss[4], ssq[4];
  int lane = threadIdx.x & 63, wv = threadIdx.x >> 6;
  if (lane == 0) { ss[wv] = s; ssq[wv] = sq; }
  __syncthreads();
  s  = ss[0] + ss[1] + ss[2] + ss[3];
  sq = ssq[0] + ssq[1] + ssq[2] + ssq[3];
  float mu  = s * (1.f / D_MODEL);
  float var = sq * (1.f / D_MODEL) - mu * mu;
  float rs  = rsqrtf(var + 1e-5f);
  float4 lw4 = ((const float4*)lw)[threadIdx.x];
  float4 lb4 = ((const float4*)lb)[threadIdx.x];
  size_t base = (size_t)row * D_MODEL + threadIdx.x * 4;
  out_bf[base + 0] = __float2bfloat16((v.x - mu) * rs * lw4.x + lb4.x);
  out_bf[base + 1] = __float2bfloat16((v.y - mu) * rs * lw4.y + lb4.y);
  out_bf[base + 2] = __float2bfloat16((v.z - mu) * rs * lw4.z + lb4.z);
  out_bf[base + 3] = __float2bfloat16((v.w - mu) * rs * lw4.w + lb4.w);
}

// ---------------------------------------------------------------- epilogues
// Fragment-granular: operator()(row, col, acc) handles rows row..row+3 at col.

struct KQVEpi {  // col<1024->k, <2048->q (prescaled), <3072->V^T (direct [b,h,d,l])
  const float* kq_b; const float* v_b;
  __hip_bfloat16* kb; __hip_bfloat16* qb; __hip_bfloat16* vt;
  __device__ void operator()(int row, int col, const floatx4& v) const {
    int b = row >> 11, l = row & (SEQ_LEN - 1);
    int which = col >> 10, c = col & (D_MODEL - 1);
    int head = c >> 6, d = c & 63;
    if (which == 2) {
      float bias = v_b[c];
      short4v o;
#pragma unroll
      for (int t = 0; t < 4; t++)
        ((__hip_bfloat16*)&o)[t] = __float2bfloat16(v[t] + bias);
      // 4 consecutive l at fixed d -> one 8B store in V^T layout
      *(short4v*)(vt + ((size_t)(b * N_HEAD + head) * HEAD_DIM + d) * SEQ_LEN + l) = o;
    } else {
      float bias = kq_b[col];
      float scale = (which == 1) ? 0.125f : 1.f;
      __hip_bfloat16* dst = (which == 0) ? kb : qb;
#pragma unroll
      for (int t = 0; t < 4; t++)
        dst[((size_t)(b * N_HEAD + head) * SEQ_LEN + l + t) * HEAD_DIM + d] =
            __float2bfloat16((v[t] + bias) * scale);
    }
  }
};

// gelu_exact via Abramowitz-Stegun 7.1.26 erf (|eps| <= 1.5e-7 absolute --
// ~3 orders below bf16 rounding). Branchless (copysign), ~15 VALU ops vs
// ocml erff's ~35+ with divergent range handling. FC dispatch 59->55.7us (R9).
__device__ __forceinline__ float fast_gelu(float x) {
  float ax = fabsf(x) * 0.70710678118654752f;
  float t  = 1.f / (1.f + 0.3275911f * ax);
  float p  = ((((1.061405429f * t - 1.453152027f) * t + 1.421413741f) * t
               - 0.284496736f) * t + 0.254829592f) * t;
  float e  = __expf(-ax * ax);
  float er = 1.f - p * e;                    // erf(|x|/sqrt2)
  return 0.5f * x * (1.f + copysignf(er, x));
}

struct FCEpi {  // act = gelu(acc + fc_b)  (bf16 out)
  const float* bias; __hip_bfloat16* act;
  __device__ void operator()(int row, int col, const floatx4& v) const {
    float bi = bias[col];
#pragma unroll
    for (int t = 0; t < 4; t++) {
      float g = fast_gelu(v[t] + bi);
      act[(size_t)(row + t) * MLP_HID + col] = __float2bfloat16(g);
    }
  }
};

struct PartEpi {  // split-K fp32 partial store (N = D_MODEL)
  float* part;
  __device__ void operator()(int row, int col, const floatx4& v) const {
    float* p = part + (size_t)blockIdx.z * ((size_t)M_TOTAL * D_MODEL) +
               (size_t)row * D_MODEL + col;
#pragma unroll
    for (int t = 0; t < 4; t++) p[(size_t)t * D_MODEL] = v[t];
  }
};

struct PartBf16Epi {  // split-K bf16 partial store (N = IN_DIM)
  __hip_bfloat16* part;
  __device__ void operator()(int row, int col, const floatx4& v) const {
    __hip_bfloat16* p = part + (size_t)blockIdx.z * ((size_t)M_TOTAL * IN_DIM) +
                        (size_t)row * IN_DIM + col;
#pragma unroll
    for (int t = 0; t < 4; t++) p[(size_t)t * IN_DIM] = __float2bfloat16(v[t]);
  }
};

// ---------------------------------------------------------------- GEMM 128x128
// C[M,N] = A[M,K] @ B[K,N], A row-major bf16, B given as B^T [N][K] bf16.
// 128x128 tile, BK=64 (32 KB LDS), 256 threads = 4 waves (2x2), wave does
// 64x64 via 4x4 mfma_f32_16x16x32_bf16 frags. XOR-swizzled staging via
// global_load_lds. ~3 blocks/CU; cross-block wave overlap hides barrier drains.
// Used for embed/kqv/ao. (XCD swizzle tried R8: FETCH unchanged, regression --
// reverted for good.)

template <class Epi>
__global__ __launch_bounds__(256) void k_gemm(const __hip_bfloat16* __restrict__ A,
                                              const __hip_bfloat16* __restrict__ Bt,
                                              int M, int N, int K, int Kchunk, Epi epi) {
  __shared__ __align__(16) short As[128 * 64];
  __shared__ __align__(16) short Bs[128 * 64];
  const int tid  = threadIdx.x;
  const int lane = tid & 63;
  const int w    = tid >> 6;
  const int wm   = (w >> 1) << 6;
  const int wn   = (w & 1) << 6;
  const int r    = lane & 15;
  const int quad = lane >> 4;
  const int m0 = blockIdx.y << 7;
  const int n0 = blockIdx.x << 7;
  const int koff = blockIdx.z * Kchunk;

  const __hip_bfloat16* pa[4];
  const __hip_bfloat16* pb[4];
#pragma unroll
  for (int j = 0; j < 4; j++) {
    int s = tid + j * 256;
    int row = s >> 3;
    int c = (s & 7) ^ (row & 7);
    pa[j] = A  + (size_t)(m0 + row) * K + (c << 3) + koff;
    pb[j] = Bt + (size_t)(n0 + row) * K + (c << 3) + koff;
  }

  floatx4 acc[4][4];
#pragma unroll
  for (int i = 0; i < 4; i++)
#pragma unroll
    for (int j = 0; j < 4; j++) acc[i][j] = (floatx4){0.f, 0.f, 0.f, 0.f};

  int aoff[2][4], boff[2][4];
#pragma unroll
  for (int kk = 0; kk < 2; kk++)
#pragma unroll
    for (int i = 0; i < 4; i++) {
      int pc = ((quad + (kk << 2)) ^ (r & 7)) << 3;
      aoff[kk][i] = (wm + i * 16 + r) * 64 + pc;
      boff[kk][i] = (wn + i * 16 + r) * 64 + pc;
    }

  for (int k0 = 0; k0 < Kchunk; k0 += 64) {
    __syncthreads();
#pragma unroll
    for (int j = 0; j < 4; j++) {
      async_copy16(pa[j] + k0, &As[(tid + j * 256) * 8]);
      async_copy16(pb[j] + k0, &Bs[(tid + j * 256) * 8]);
    }
    __syncthreads();
#pragma unroll
    for (int kk = 0; kk < 2; kk++) {
      short8 fa[4], fb[4];
#pragma unroll
      for (int i = 0; i < 4; i++) {
        fa[i] = *(const short8*)&As[aoff[kk][i]];
        fb[i] = *(const short8*)&Bs[boff[kk][i]];
      }
#pragma unroll
      for (int i = 0; i < 4; i++)
#pragma unroll
        for (int j = 0; j < 4; j++)
          acc[i][j] = __builtin_amdgcn_mfma_f32_16x16x32_bf16(fa[i], fb[j], acc[i][j], 0, 0, 0);
    }
  }

#pragma unroll
  for (int i = 0; i < 4; i++)
#pragma unroll
    for (int j = 0; j < 4; j++)
      epi(m0 + wm + i * 16 + quad * 4, n0 + wn + j * 16 + r, acc[i][j]);
}

template <class Epi>
static void launch_gemm(const __hip_bfloat16* A, const __hip_bfloat16* Bt,
                        int M, int N, int K, Epi epi, hipStream_t s) {
  dim3 grid(N / 128, M / 128, 1);
  k_gemm<Epi><<<grid, 256, 0, s>>>(A, Bt, M, N, K, K, epi);
}

// ---------------------------------------------------------------- GEMM 256x256 (8-phase)
// Used for FC + proj. Register-pinned: VGPR 120 + 128 AGPR acc = 248/256 --
// max 2 waves/SIMD => 1 block/CU; no deeper lookahead possible.

#define STAGE_A(BUF, H, KT)                                                       \
  do {                                                                            \
    async_copy16(ga + (size_t)((H) * 128) * K + (KT) * 64,                        \
                 &As[BUF][(tid + (H) * 1024) * 8]);                               \
    async_copy16(ga + (size_t)((H) * 128 + 64) * K + (KT) * 64,                   \
                 &As[BUF][(tid + (H) * 1024 + 512) * 8]);                         \
  } while (0)

#define STAGE_B(BUF, H, KT)                                                       \
  do {                                                                            \
    async_copy16(gb + (size_t)((H) * 128) * K + (KT) * 64,                        \
                 &Bs[BUF][(tid + (H) * 1024) * 8]);                               \
    async_copy16(gb + (size_t)((H) * 128 + 64) * K + (KT) * 64,                   \
                 &Bs[BUF][(tid + (H) * 1024 + 512) * 8]);                         \
  } while (0)

#define MFMA_BLK(IO, JO, BFX)                                                     \
  _Pragma("unroll") for (int i = 0; i < 4; i++) {                                 \
    _Pragma("unroll") for (int j = 0; j < 2; j++) {                               \
      acc[(IO) + i][(JO) + j] = __builtin_amdgcn_mfma_f32_16x16x32_bf16(          \
          af[i][0], BFX[j][0], acc[(IO) + i][(JO) + j], 0, 0, 0);                 \
      acc[(IO) + i][(JO) + j] = __builtin_amdgcn_mfma_f32_16x16x32_bf16(          \
          af[i][1], BFX[j][1], acc[(IO) + i][(JO) + j], 0, 0, 0);                 \
    }                                                                             \
  }

#define GTILE(T, BUF)                                                             \
  {                                                                               \
    _Pragma("unroll") for (int i = 0; i < 4; i++) {                               \
      af[i][0] = *(const short8*)&As[BUF][arb[i] + pc0];                          \
      af[i][1] = *(const short8*)&As[BUF][arb[i] + pc1];                          \
    }                                                                             \
    _Pragma("unroll") for (int j = 0; j < 2; j++) {                               \
      bf0[j][0] = *(const short8*)&Bs[BUF][brb[j] + pc0];                         \
      bf0[j][1] = *(const short8*)&Bs[BUF][brb[j] + pc1];                         \
    }                                                                             \
    if ((T) + 1 < nt) { STAGE_A((BUF) ^ 1, 1, (T) + 1); }                         \
    __builtin_amdgcn_s_barrier();                                                 \
    asm volatile("s_waitcnt lgkmcnt(0)" ::: "memory");                            \
    __builtin_amdgcn_s_setprio(1);                                                \
    MFMA_BLK(0, 0, bf0)                                                           \
    __builtin_amdgcn_s_setprio(0);                                                \
    __builtin_amdgcn_s_barrier();                                                 \
    _Pragma("unroll") for (int j = 0; j < 2; j++) {                               \
      bf1[j][0] = *(const short8*)&Bs[BUF][brb[j] + 8192 + pc0];                  \
      bf1[j][1] = *(const short8*)&Bs[BUF][brb[j] + 8192 + pc1];                  \
    }                                                                             \
    if ((T) + 2 < nt) { STAGE_A(BUF, 0, (T) + 2); }                               \
    __builtin_amdgcn_s_barrier();                                                 \
    asm volatile("s_waitcnt lgkmcnt(0)" ::: "memory");                            \
    __builtin_amdgcn_s_setprio(1);                                                \
    MFMA_BLK(0, 2, bf1)                                                           \
    __builtin_amdgcn_s_setprio(0);                                                \
    __builtin_amdgcn_s_barrier();                                                 \
    _Pragma("unroll") for (int i = 0; i < 4; i++) {                               \
      af[i][0] = *(const short8*)&As[BUF][arb[i] + 8192 + pc0];                   \
      af[i][1] = *(const short8*)&As[BUF][arb[i] + 8192 + pc1];                   \
    }                                                                             \
    if ((T) + 2 < nt) { STAGE_B(BUF, 0, (T) + 2); }                               \
    __builtin_amdgcn_s_barrier();                                                 \
    asm volatile("s_waitcnt lgkmcnt(0)" ::: "memory");                            \
    __builtin_amdgcn_s_setprio(1);                                                \
    MFMA_BLK(4, 0, bf0)                                                           \
    __builtin_amdgcn_s_setprio(0);                                                \
    __builtin_amdgcn_s_barrier();                                                 \
    if ((T) + 2 < nt) { STAGE_B(BUF, 1, (T) + 2); }                               \
    __builtin_amdgcn_s_setprio(1);                                                \
    MFMA_BLK(4, 2, bf1)                                                           \
    __builtin_amdgcn_s_setprio(0);                                                \
    if ((T) + 2 < nt) {                                                           \
      asm volatile("s_waitcnt vmcnt(6)" ::: "memory");                            \
    } else {                                                                      \
      asm volatile("s_waitcnt vmcnt(0)" ::: "memory");                            \
    }                                                                             \
    __builtin_amdgcn_s_barrier();                                                 \
  }

template <class Epi>
__global__ __launch_bounds__(512, 2) void k_gemm256(const __hip_bfloat16* __restrict__ A,
                                                    const __hip_bfloat16* __restrict__ Bt,
                                                    int M, int N, int K, int Kchunk, Epi epi) {
  (void)M; (void)N;
  __shared__ __align__(16) short As[2][16384];   // 2 x 32 KB
  __shared__ __align__(16) short Bs[2][16384];   // 2 x 32 KB
  const int tid  = threadIdx.x;
  const int lane = tid & 63;
  const int w    = tid >> 6;        // 0..7
  const int wr   = w >> 2;          // 0..1
  const int wc   = w & 3;           // 0..3
  const int r    = lane & 15;
  const int quad = lane >> 4;
  const int m0 = blockIdx.y << 8;
  const int n0 = blockIdx.x << 8;
  const int koff = blockIdx.z * Kchunk;
  const int nt = Kchunk >> 6;       // K-tiles; must be even

  const int sr = tid >> 3;                     // 0..63
  const int sc = (tid & 7) ^ (sr & 7);
  const __hip_bfloat16* ga = A  + (size_t)(m0 + sr) * K + sc * 8 + koff;
  const __hip_bfloat16* gb = Bt + (size_t)(n0 + sr) * K + sc * 8 + koff;

  const int pc0 = ((quad    ) ^ (r & 7)) << 3;
  const int pc1 = ((quad + 4) ^ (r & 7)) << 3;
  int arb[4], brb[2];
#pragma unroll
  for (int i = 0; i < 4; i++) arb[i] = ((2 * i + wr) * 16 + r) * 64;
#pragma unroll
  for (int j = 0; j < 2; j++) brb[j] = ((4 * j + wc) * 16 + r) * 64;

  floatx4 acc[8][4];
#pragma unroll
  for (int i = 0; i < 8; i++)
#pragma unroll
    for (int j = 0; j < 4; j++) acc[i][j] = (floatx4){0.f, 0.f, 0.f, 0.f};
  short8 af[4][2], bf0[2][2], bf1[2][2];

  STAGE_A(0, 0, 0);
  STAGE_B(0, 0, 0);
  STAGE_B(0, 1, 0);
  STAGE_A(0, 1, 0);
  if (nt > 1) {
    STAGE_A(1, 0, 1);
    STAGE_B(1, 0, 1);
    STAGE_B(1, 1, 1);
    asm volatile("s_waitcnt vmcnt(6)" ::: "memory");
  } else {
    asm volatile("s_waitcnt vmcnt(0)" ::: "memory");
  }
  __builtin_amdgcn_s_barrier();

  for (int t = 0; t < nt; t += 2) {
    GTILE(t, 0)
    GTILE(t + 1, 1)
  }

#pragma unroll
  for (int i = 0; i < 8; i++)
#pragma unroll
    for (int j = 0; j < 4; j++)
      epi(m0 + (2 * i + wr) * 16 + quad * 4, n0 + (4 * j + wc) * 16 + r, acc[i][j]);
}

// ---------------------------------------------------------------- flash attention
// v4: 256 threads = 4 waves, wave owns 16 q-rows, block = 64 q-rows ->
// 1024 blocks (32 strips x 32 bh): fine-grained longest-first packing +
// ~3 blocks/CU resident (LDS 41 KB) for cross-block overlap; barriers sync
// only 4 waves. Double-buffered K/V via global_load_lds; counted vmcnt(4)
// pipeline, never drains to 0 mid-loop. Odd ktiles via guarded second ATILE.
// XOR-swizzle; S^T = K Q^T, p=exp(s) (scores bounded), deferred l; P^T via
// per-wave LDS; O^T += V^T P^T.

#define PSTR 68   // bf16 elems per q-row in P buffer

#define STAGE_KV(T, P)                                                         \
  do {                                                                         \
    async_copy16(kp + (size_t)((((T) << 6)) + row0) * HEAD_DIM + g0 * 8,       \
                 &Ks[P][c0 * 8]);                                              \
    async_copy16(kp + (size_t)((((T) << 6)) + row1) * HEAD_DIM + g1 * 8,       \
                 &Ks[P][c1 * 8]);                                              \
    async_copy16(vp + (size_t)row0 * SEQ_LEN + ((T) << 6) + g0 * 8,            \
                 &Vs[P][c0 * 8]);                                              \
    async_copy16(vp + (size_t)row1 * SEQ_LEN + ((T) << 6) + g1 * 8,            \
                 &Vs[P][c1 * 8]);                                              \
  } while (0)

#define QKSUB(KT, P)                                                           \
  {                                                                            \
    const int tss = ts + ((KT) << 4);                                          \
    short4v pk0;                                                               \
    if (tss < qend) {                                                          \
      const int krow = ((KT) << 4) + r;                                        \
      short8 a0 = *(const short8*)&Ks[P][(krow * 8 + (quad ^ sw)) * 8];        \
      short8 a1 = *(const short8*)&Ks[P][(krow * 8 + ((quad ^ sw) ^ 4)) * 8];  \
      floatx4 s0 = (floatx4){0.f, 0.f, 0.f, 0.f};                              \
      s0 = __builtin_amdgcn_mfma_f32_16x16x32_bf16(a0, qf0, s0, 0, 0, 0);      \
      s0 = __builtin_amdgcn_mfma_f32_16x16x32_bf16(a1, qf1, s0, 0, 0, 0);      \
      if (tss + 15 > qbw) {                                                    \
        int off0 = qbw + r - tss;                                              \
        _Pragma("unroll") for (int tt = 0; tt < 4; tt++) {                     \
          int kl = (quad << 2) + tt;                                           \
          if (kl > off0) s0[tt] = -INFINITY;                                   \
        }                                                                      \
      }                                                                        \
      _Pragma("unroll") for (int tt = 0; tt < 4; tt++) {                       \
        float e0 = __expf(s0[tt]); ls0 += e0;                                  \
        ((__hip_bfloat16*)&pk0)[tt] = __float2bfloat16(e0);                    \
      }                                                                        \
    } else {                                                                   \
      pk0 = (short4v){0, 0, 0, 0};                                             \
    }                                                                          \
    *(short4v*)(pw + r * PSTR + ((KT) << 4) + (quad << 2)) = pk0;              \
  }

#define ATILE(T, P)                                                            \
  {                                                                            \
    const int ts = (T) << 6;                                                   \
    QKSUB(0, P)                                                                \
    QKSUB(1, P)                                                                \
    QKSUB(2, P)                                                                \
    QKSUB(3, P)                                                                \
    __builtin_amdgcn_s_setprio(1);                                             \
    _Pragma("unroll") for (int c = 0; c < 2; c++) {                            \
      short8 pb0 = *(const short8*)(pw + r * PSTR + (c << 5) + (quad << 3));   \
      _Pragma("unroll") for (int fd = 0; fd < 4; fd++) {                       \
        const int vrow = (fd << 4) + r;                                        \
        short8 va = *(const short8*)&Vs[P][(vrow * 8 + (((c << 2) + quad) ^ sw)) * 8]; \
        of[fd] = __builtin_amdgcn_mfma_f32_16x16x32_bf16(va, pb0, of[fd], 0, 0, 0); \
      }                                                                        \
    }                                                                          \
    __builtin_amdgcn_s_setprio(0);                                             \
    __builtin_amdgcn_s_barrier();                                              \
    if ((T) + 2 < ktiles) {                                                    \
      STAGE_KV((T) + 2, P);                                                    \
      asm volatile("s_waitcnt vmcnt(4)" ::: "memory");                         \
    } else {                                                                   \
      asm volatile("s_waitcnt vmcnt(0)" ::: "memory");                         \
    }                                                                          \
    __builtin_amdgcn_s_barrier();                                              \
    __builtin_amdgcn_sched_barrier(0);                                         \
  }

__global__ __launch_bounds__(256, 3) void k_flash_attn(const __hip_bfloat16* __restrict__ kb,
                                                       const __hip_bfloat16* __restrict__ qb,
                                                       const __hip_bfloat16* __restrict__ vtb,
                                                       __hip_bfloat16* __restrict__ ob) {
  __shared__ __align__(16) short Ks[2][64 * 64];         // 16 KB
  __shared__ __align__(16) short Vs[2][64 * 64];         // 16 KB
  __shared__ __align__(16) __hip_bfloat16 Pb[4][16 * PSTR];  // 8.5 KB
  const int tid  = threadIdx.x;
  const int lane = tid & 63;
  const int w    = tid >> 6;                         // 0..3
  const int r    = lane & 15;
  const int quad = lane >> 4;
  const int sw   = r & 7;
  const int bh    = blockIdx.x & 31;                 // 32 (b,h)
  const int strip = (SEQ_LEN / 64 - 1) - (blockIdx.x >> 5);  // longest first
  const int qb0   = strip << 6;                      // block q start (64 rows)
  const int qbw   = qb0 + (w << 4);                  // wave q start (16 rows)
  const int qend  = qbw + 16;
  const int b = bh >> 4, h = bh & (N_HEAD - 1);

  const __hip_bfloat16* qp = qb  + ((size_t)bh * SEQ_LEN + qbw) * HEAD_DIM;
  const __hip_bfloat16* kp = kb  + (size_t)bh * SEQ_LEN * HEAD_DIM;
  const __hip_bfloat16* vp = vtb + (size_t)bh * HEAD_DIM * SEQ_LEN;  // [d][l]
  __hip_bfloat16* pw = &Pb[w][0];

  short8 qf0 = *(const short8*)(qp + r * HEAD_DIM + quad * 8);
  short8 qf1 = *(const short8*)(qp + r * HEAD_DIM + quad * 8 + 32);

  floatx4 of[4];
#pragma unroll
  for (int i = 0; i < 4; i++) of[i] = (floatx4){0.f, 0.f, 0.f, 0.f};
  float ls0 = 0.f;

  // staging: thread tid stages chunks tid and tid+256 of each 64x64 tile
  const int c0 = tid, c1 = tid + 256;
  const int row0 = c0 >> 3, g0 = (c0 & 7) ^ (row0 & 7);
  const int row1 = c1 >> 3, g1 = (c1 & 7) ^ (row1 & 7);

  const int ktiles = strip + 1;   // may be odd
  STAGE_KV(0, 0);
  if (ktiles > 1) {
    STAGE_KV(1, 1);
    asm volatile("s_waitcnt vmcnt(4)" ::: "memory");
  } else {
    asm volatile("s_waitcnt vmcnt(0)" ::: "memory");
  }
  __builtin_amdgcn_s_barrier();
  __builtin_amdgcn_sched_barrier(0);

  for (int t = 0; t < ktiles; t += 2) {
    ATILE(t, 0)
    if (t + 1 < ktiles) { ATILE(t + 1, 1) }
  }

  ls0 += __shfl_xor(ls0, 16); ls0 += __shfl_xor(ls0, 32);
  float inv0 = 1.f / ls0;

  size_t orow = ((size_t)b * SEQ_LEN + qbw + r) * D_MODEL + (size_t)h * HEAD_DIM;
#pragma unroll
  for (int fd = 0; fd < 4; fd++) {
    short4v o4;
#pragma unroll
    for (int tt = 0; tt < 4; tt++)
      ((__hip_bfloat16*)&o4)[tt] = __float2bfloat16(of[fd][tt] * inv0);
    *(short4v*)(ob + orow + fd * 16 + quad * 4) = o4;
  }
}

// ---------------------------------------------------------------- driver

extern "C" void kernel_launch(void* const* d_in, const int* in_sizes, int n_in,
                              void* d_out, int out_size, void* d_ws, size_t ws_size,
                              hipStream_t stream) {
  (void)in_sizes; (void)n_in; (void)out_size; (void)ws_size;
  const float* x      = (const float*)d_in[0];
  const float* wte_w  = (const float*)d_in[1];
  const float* wte_b  = (const float*)d_in[2];
  const float* wpe    = (const float*)d_in[3];
  const float* ln1_w  = (const float*)d_in[4];
  const float* ln1_b  = (const float*)d_in[5];
  const float* kq_w   = (const float*)d_in[6];
  const float* kq_b   = (const float*)d_in[7];
  const float* v_w    = (const float*)d_in[8];
  const float* v_b    = (const float*)d_in[9];
  const float* ao_w   = (const float*)d_in[10];
  const float* ao_b   = (const float*)d_in[11];
  const float* ln2_w  = (const float*)d_in[12];
  const float* ln2_b  = (const float*)d_in[13];
  const float* fc_w   = (const float*)d_in[14];
  const float* fc_b   = (const float*)d_in[15];
  const float* proj_w = (const float*)d_in[16];
  const float* proj_b = (const float*)d_in[17];

  float* out0     = (float*)d_out;                                  // (B,L,512)
  float* attn_out = out0 + (size_t)M_TOTAL * IN_DIM;                // (B,L,1024)

  char* ws = (char*)d_ws;
  // layout (MB): wT_all [0,22) | x_bf [22,26) | R1 [26,58) | k [58,66) |
  //              q [66,74) | vt [74,82) | o [82,90) | hn [90,98)
  __hip_bfloat16* wT    = (__hip_bfloat16*)ws;
  __hip_bfloat16* x_bf  = (__hip_bfloat16*)(ws + 22 * 1048576);
  char* R1              = ws + 26 * 1048576;                         // embed_part / ao_part / act
  float* embed_part     = (float*)R1;
  float* ao_part        = (float*)R1;
  __hip_bfloat16* act   = (__hip_bfloat16*)R1;
  __hip_bfloat16* k_bf  = (__hip_bfloat16*)(ws + 58 * 1048576);
  __hip_bfloat16* q_bf  = (__hip_bfloat16*)(ws + 66 * 1048576);
  __hip_bfloat16* vt_bf = (__hip_bfloat16*)(ws + 74 * 1048576);
  __hip_bfloat16* o_bf  = (__hip_bfloat16*)(ws + 82 * 1048576);
  __hip_bfloat16* hn_bf = (__hip_bfloat16*)(ws + 90 * 1048576);
  __hip_bfloat16* xo_bf = k_bf;                                      // k dead after attn
  __hip_bfloat16* proj_part = k_bf;                                  // 32 MB over k/q/vt/o (dead at step 9)

  // wT sub-offsets (bf16 elements)
  __hip_bfloat16* wteT  = wT;            // [512][1024]^T  -> [1024][512]
  __hip_bfloat16* kqvT  = wT +  524288;  // kq^T [2048][1024] then v^T [1024][1024] (contiguous)
  __hip_bfloat16* aoT   = wT + 3670016;
  __hip_bfloat16* fcT   = wT + 4718592;
  __hip_bfloat16* projT = wT + 8912896;

  // 1. fused prep: all 6 weight transposes + x convert (inputs only)
  k_prep<<<4736, 256, 0, stream>>>(wte_w, kq_w, v_w, ao_w, fc_w, proj_w, x, wT, x_bf);

  // 2. embed GEMM: split-K x2 fp32 partials
  {
    dim3 grid(D_MODEL / 128, M_TOTAL / 128, 2);
    k_gemm<PartEpi><<<grid, 256, 0, stream>>>(x_bf, wteT, M_TOTAL, D_MODEL, IN_DIM, IN_DIM / 2,
                                              PartEpi{embed_part});
  }

  // 3. hn = LN1(part0 + part1 + wte_b + wpe)
  k_ln1_combine<<<M_TOTAL, 256, 0, stream>>>(embed_part, wte_b, wpe, ln1_w, ln1_b, hn_bf);

  // 4. fused kqv = hn @ [kq_w | v_w]  (N=3072, 768 blocks); V^T written directly
  launch_gemm(hn_bf, kqvT, M_TOTAL, 3 * D_MODEL, D_MODEL,
              KQVEpi{kq_b, v_b, k_bf, q_bf, vt_bf}, stream);

  // 5. flash attention -> o  [b,l,h*d] bf16  (64-row blocks, 1024 blocks)
  k_flash_attn<<<(SEQ_LEN / 64) * 32, 256, 0, stream>>>(k_bf, q_bf, vt_bf, o_bf);

  // 6. ao GEMM: split-K x2 fp32 partials
  {
    dim3 grid(D_MODEL / 128, M_TOTAL / 128, 2);
    k_gemm<PartEpi><<<grid, 256, 0, stream>>>(o_bf, aoT, M_TOTAL, D_MODEL, D_MODEL, D_MODEL / 2,
                                              PartEpi{ao_part});
  }

  // 7. attn_out = part0+part1+ao_b+hn (to d_out); xo = LN2(attn_out)
  k_ln2_combine<<<M_TOTAL, 256, 0, stream>>>(ao_part, ao_b, hn_bf, ln2_w, ln2_b, attn_out, xo_bf);

  // 8. act = gelu(xo @ fc_w + fc_b)   (256^2 8-phase, 256 blocks, nt=16)
  {
    dim3 grid(MLP_HID / 256, M_TOTAL / 256, 1);
    k_gemm256<FCEpi><<<grid, 512, 0, stream>>>(xo_bf, fcT, M_TOTAL, MLP_HID, D_MODEL, D_MODEL,
                                               FCEpi{fc_b, act});
  }

  // 9. out = act @ proj_w + proj_b  (256^2 8-phase, split-K x8 bf16 partials; nt=8)
  {
    dim3 grid(IN_DIM / 256, M_TOTAL / 256, 8);
    k_gemm256<PartBf16Epi><<<grid, 512, 0, stream>>>(act, projT, M_TOTAL, IN_DIM, MLP_HID,
                                                     MLP_HID / 8, PartBf16Epi{proj_part});
  }
  k_reduce_proj<<<M_TOTAL * IN_DIM / 8 / 256, 256, 0, stream>>>(proj_part, proj_b, out0);
}

// Round 11
// 345.116 us; speedup vs baseline: 1.0383x; 1.0124x over previous
//
#include <hip/hip_runtime.h>
#include <hip/hip_bf16.h>
#include <cmath>

#define D_MODEL   1024
#define N_HEAD    16
#define HEAD_DIM  64
#define SEQ_LEN   2048
#define NBATCH    2
#define M_TOTAL   (NBATCH * SEQ_LEN)   // 4096
#define IN_DIM    512
#define MLP_HID   4096

typedef __attribute__((ext_vector_type(8))) short short8;
typedef __attribute__((ext_vector_type(4))) short short4v;
typedef __attribute__((ext_vector_type(4))) float floatx4;

typedef const __attribute__((address_space(1))) void* gas_ptr;
typedef __attribute__((address_space(3))) void* las_ptr;

__device__ __forceinline__ void async_copy16(const void* g, void* l) {
  __builtin_amdgcn_global_load_lds((gas_ptr)g, (las_ptr)l, 16, 0, 0);
}

// ---------------------------------------------------------------- fused input prep
// ONE launch at t=0: all 6 weight transposes (fp32 [K][N] -> bf16 [N][K]) plus
// the x fp32->bf16 convert. 64x64 tiles, short8 coalesced stores (16B/lane,
// 128B runs). Measured: -8us vs 32x32 scalar-store version (R10 vs R9).

__global__ __launch_bounds__(256) void k_prep(const float* __restrict__ wte_w,
                                              const float* __restrict__ kq_w,
                                              const float* __restrict__ v_w,
                                              const float* __restrict__ ao_w,
                                              const float* __restrict__ fc_w,
                                              const float* __restrict__ proj_w,
                                              const float* __restrict__ x,
                                              __hip_bfloat16* __restrict__ wT,
                                              __hip_bfloat16* __restrict__ x_bf) {
  const int bid = blockIdx.x;
  const float* in; __hip_bfloat16* out; int K, N, local;
  if (bid < 128)        { in = wte_w;  out = wT;           K = IN_DIM;  N = D_MODEL;     local = bid;        }
  else if (bid < 640)   { in = kq_w;   out = wT +  524288; K = D_MODEL; N = 2 * D_MODEL; local = bid - 128;  }
  else if (bid < 896)   { in = v_w;    out = wT + 2621440; K = D_MODEL; N = D_MODEL;     local = bid - 640;  }
  else if (bid < 1152)  { in = ao_w;   out = wT + 3670016; K = D_MODEL; N = D_MODEL;     local = bid - 896;  }
  else if (bid < 2176)  { in = fc_w;   out = wT + 4718592; K = D_MODEL; N = MLP_HID;     local = bid - 1152; }
  else if (bid < 2688)  { in = proj_w; out = wT + 8912896; K = MLP_HID; N = IN_DIM;      local = bid - 2176; }
  else {  // convert x: 2048 blocks x 256 float4
    int i = (bid - 2688) * 256 + threadIdx.x;
    float4 v = ((const float4*)x)[i];
    short4v o;
    ((__hip_bfloat16*)&o)[0] = __float2bfloat16(v.x);
    ((__hip_bfloat16*)&o)[1] = __float2bfloat16(v.y);
    ((__hip_bfloat16*)&o)[2] = __float2bfloat16(v.z);
    ((__hip_bfloat16*)&o)[3] = __float2bfloat16(v.w);
    ((short4v*)x_bf)[i] = o;
    return;
  }
  __shared__ __hip_bfloat16 t[64][73];
  const int ntx = N >> 6;
  const int n0 = (local % ntx) * 64, k0 = (local / ntx) * 64;
  const int tx = threadIdx.x & 7, ty = threadIdx.x >> 3;  // 8 x 32
#pragma unroll
  for (int i = 0; i < 64; i += 32) {
    const float* src = in + (size_t)(k0 + ty + i) * N + n0 + tx * 8;
    float4 v0 = ((const float4*)src)[0];
    float4 v1 = ((const float4*)src)[1];
    t[ty + i][tx * 8 + 0] = __float2bfloat16(v0.x);
    t[ty + i][tx * 8 + 1] = __float2bfloat16(v0.y);
    t[ty + i][tx * 8 + 2] = __float2bfloat16(v0.z);
    t[ty + i][tx * 8 + 3] = __float2bfloat16(v0.w);
    t[ty + i][tx * 8 + 4] = __float2bfloat16(v1.x);
    t[ty + i][tx * 8 + 5] = __float2bfloat16(v1.y);
    t[ty + i][tx * 8 + 6] = __float2bfloat16(v1.z);
    t[ty + i][tx * 8 + 7] = __float2bfloat16(v1.w);
  }
  __syncthreads();
#pragma unroll
  for (int i = 0; i < 64; i += 32) {
    int nr = ty + i;
    short8 o;
#pragma unroll
    for (int j = 0; j < 8; j++) ((__hip_bfloat16*)&o)[j] = t[tx * 8 + j][nr];
    *(short8*)(out + (size_t)(n0 + nr) * K + k0 + tx * 8) = o;
  }
}

// out0 = bias + sum of 8 split-K bf16 partials (8 outputs/thread, short8 loads)
__global__ __launch_bounds__(256) void k_reduce_proj(const __hip_bfloat16* __restrict__ part,
                                                     const float* __restrict__ bias,
                                                     float* __restrict__ out) {
  int i = blockIdx.x * 256 + threadIdx.x;          // over M_TOTAL*IN_DIM/8
  const size_t SP8 = (size_t)M_TOTAL * IN_DIM / 8; // short8 groups per split
  int cb = (i & (IN_DIM / 8 - 1)) * 2;             // float4 index of bias
  float4 s0 = ((const float4*)bias)[cb];
  float4 s1 = ((const float4*)bias)[cb + 1];
#pragma unroll
  for (int j = 0; j < 8; j++) {
    short8 v = ((const short8*)part)[i + j * SP8];
    s0.x += __bfloat162float(((const __hip_bfloat16*)&v)[0]);
    s0.y += __bfloat162float(((const __hip_bfloat16*)&v)[1]);
    s0.z += __bfloat162float(((const __hip_bfloat16*)&v)[2]);
    s0.w += __bfloat162float(((const __hip_bfloat16*)&v)[3]);
    s1.x += __bfloat162float(((const __hip_bfloat16*)&v)[4]);
    s1.y += __bfloat162float(((const __hip_bfloat16*)&v)[5]);
    s1.z += __bfloat162float(((const __hip_bfloat16*)&v)[6]);
    s1.w += __bfloat162float(((const __hip_bfloat16*)&v)[7]);
  }
  ((float4*)out)[i * 2]     = s0;
  ((float4*)out)[i * 2 + 1] = s1;
}

// ---------------------------------------------------------------- fused combine + layernorm

// hn = LN(part0 + part1 + wte_b + wpe[l])   -- embed combine fused, no h buffer
__global__ __launch_bounds__(256) void k_ln1_combine(const float* __restrict__ part,
                                                     const float* __restrict__ wb,
                                                     const float* __restrict__ wpe,
                                                     const float* __restrict__ lw,
                                                     const float* __restrict__ lb,
                                                     __hip_bfloat16* __restrict__ out_bf) {
  int row = blockIdx.x;
  int l = row & (SEQ_LEN - 1);
  float4 a = ((const float4*)(part + (size_t)row * D_MODEL))[threadIdx.x];
  float4 c = ((const float4*)(part + (size_t)(M_TOTAL + row) * D_MODEL))[threadIdx.x];
  float4 wb4 = ((const float4*)wb)[threadIdx.x];
  float4 pe4 = ((const float4*)(wpe + (size_t)l * D_MODEL))[threadIdx.x];
  float4 v;
  v.x = a.x + c.x + wb4.x + pe4.x;
  v.y = a.y + c.y + wb4.y + pe4.y;
  v.z = a.z + c.z + wb4.z + pe4.z;
  v.w = a.w + c.w + wb4.w + pe4.w;
  float s  = v.x + v.y + v.z + v.w;
  float sq = v.x * v.x + v.y * v.y + v.z * v.z + v.w * v.w;
#pragma unroll
  for (int o = 1; o < 64; o <<= 1) { s += __shfl_xor(s, o); sq += __shfl_xor(sq, o); }
  __shared__ float ss[4], ssq[4];
  int lane = threadIdx.x & 63, wv = threadIdx.x >> 6;
  if (lane == 0) { ss[wv] = s; ssq[wv] = sq; }
  __syncthreads();
  s  = ss[0] + ss[1] + ss[2] + ss[3];
  sq = ssq[0] + ssq[1] + ssq[2] + ssq[3];
  float mu  = s * (1.f / D_MODEL);
  float var = sq * (1.f / D_MODEL) - mu * mu;
  float rs  = rsqrtf(var + 1e-5f);
  float4 lw4 = ((const float4*)lw)[threadIdx.x];
  float4 lb4 = ((const float4*)lb)[threadIdx.x];
  size_t base = (size_t)row * D_MODEL + threadIdx.x * 4;
  out_bf[base + 0] = __float2bfloat16((v.x - mu) * rs * lw4.x + lb4.x);
  out_bf[base + 1] = __float2bfloat16((v.y - mu) * rs * lw4.y + lb4.y);
  out_bf[base + 2] = __float2bfloat16((v.z - mu) * rs * lw4.z + lb4.z);
  out_bf[base + 3] = __float2bfloat16((v.w - mu) * rs * lw4.w + lb4.w);
}

// attn_out = part0 + part1 + ao_b + hn (fp32, to d_out); xo = LN(attn_out)
__global__ __launch_bounds__(256) void k_ln2_combine(const float* __restrict__ part,
                                                     const float* __restrict__ bias,
                                                     const __hip_bfloat16* __restrict__ hn,
                                                     const float* __restrict__ lw,
                                                     const float* __restrict__ lb,
                                                     float* __restrict__ attn_out,
                                                     __hip_bfloat16* __restrict__ out_bf) {
  int row = blockIdx.x;
  float4 a = ((const float4*)(part + (size_t)row * D_MODEL))[threadIdx.x];
  float4 c = ((const float4*)(part + (size_t)(M_TOTAL + row) * D_MODEL))[threadIdx.x];
  float4 b4 = ((const float4*)bias)[threadIdx.x];
  short4v h4 = ((const short4v*)(hn + (size_t)row * D_MODEL))[threadIdx.x];
  float4 v;
  v.x = a.x + c.x + b4.x + __bfloat162float(((const __hip_bfloat16*)&h4)[0]);
  v.y = a.y + c.y + b4.y + __bfloat162float(((const __hip_bfloat16*)&h4)[1]);
  v.z = a.z + c.z + b4.z + __bfloat162float(((const __hip_bfloat16*)&h4)[2]);
  v.w = a.w + c.w + b4.w + __bfloat162float(((const __hip_bfloat16*)&h4)[3]);
  ((float4*)(attn_out + (size_t)row * D_MODEL))[threadIdx.x] = v;
  float s  = v.x + v.y + v.z + v.w;
  float sq = v.x * v.x + v.y * v.y + v.z * v.z + v.w * v.w;
#pragma unroll
  for (int o = 1; o < 64; o <<= 1) { s += __shfl_xor(s, o); sq += __shfl_xor(sq, o); }
  __shared__ float ss[4], ssq[4];
  int lane = threadIdx.x & 63, wv = threadIdx.x >> 6;
  if (lane == 0) { ss[wv] = s; ssq[wv] = sq; }
  __syncthreads();
  s  = ss[0] + ss[1] + ss[2] + ss[3];
  sq = ssq[0] + ssq[1] + ssq[2] + ssq[3];
  float mu  = s * (1.f / D_MODEL);
  float var = sq * (1.f / D_MODEL) - mu * mu;
  float rs  = rsqrtf(var + 1e-5f);
  float4 lw4 = ((const float4*)lw)[threadIdx.x];
  float4 lb4 = ((const float4*)lb)[threadIdx.x];
  size_t base = (size_t)row * D_MODEL + threadIdx.x * 4;
  out_bf[base + 0] = __float2bfloat16((v.x - mu) * rs * lw4.x + lb4.x);
  out_bf[base + 1] = __float2bfloat16((v.y - mu) * rs * lw4.y + lb4.y);
  out_bf[base + 2] = __float2bfloat16((v.z - mu) * rs * lw4.z + lb4.z);
  out_bf[base + 3] = __float2bfloat16((v.w - mu) * rs * lw4.w + lb4.w);
}

// ---------------------------------------------------------------- epilogues
// Fragment-granular: operator()(row, col, acc) handles rows row..row+3 at col.

struct KQVEpi {  // col<1024->k, <2048->q (prescaled), <3072->V^T (direct [b,h,d,l])
  const float* kq_b; const float* v_b;
  __hip_bfloat16* kb; __hip_bfloat16* qb; __hip_bfloat16* vt;
  __device__ void operator()(int row, int col, const floatx4& v) const {
    int b = row >> 11, l = row & (SEQ_LEN - 1);
    int which = col >> 10, c = col & (D_MODEL - 1);
    int head = c >> 6, d = c & 63;
    if (which == 2) {
      float bias = v_b[c];
      short4v o;
#pragma unroll
      for (int t = 0; t < 4; t++)
        ((__hip_bfloat16*)&o)[t] = __float2bfloat16(v[t] + bias);
      // 4 consecutive l at fixed d -> one 8B store in V^T layout
      *(short4v*)(vt + ((size_t)(b * N_HEAD + head) * HEAD_DIM + d) * SEQ_LEN + l) = o;
    } else {
      float bias = kq_b[col];
      float scale = (which == 1) ? 0.125f : 1.f;
      __hip_bfloat16* dst = (which == 0) ? kb : qb;
#pragma unroll
      for (int t = 0; t < 4; t++)
        dst[((size_t)(b * N_HEAD + head) * SEQ_LEN + l + t) * HEAD_DIM + d] =
            __float2bfloat16((v[t] + bias) * scale);
    }
  }
};

// gelu_exact via Abramowitz-Stegun 7.1.26 erf (|eps| <= 1.5e-7 absolute --
// ~3 orders below bf16 rounding). Branchless (copysign), ~15 VALU ops vs
// ocml erff's ~35+ with divergent range handling. FC dispatch 59->55.7us (R9).
__device__ __forceinline__ float fast_gelu(float x) {
  float ax = fabsf(x) * 0.70710678118654752f;
  float t  = 1.f / (1.f + 0.3275911f * ax);
  float p  = ((((1.061405429f * t - 1.453152027f) * t + 1.421413741f) * t
               - 0.284496736f) * t + 0.254829592f) * t;
  float e  = __expf(-ax * ax);
  float er = 1.f - p * e;                    // erf(|x|/sqrt2)
  return 0.5f * x * (1.f + copysignf(er, x));
}

struct FCEpi {  // act = gelu(acc + fc_b)  (bf16 out)
  const float* bias; __hip_bfloat16* act;
  __device__ void operator()(int row, int col, const floatx4& v) const {
    float bi = bias[col];
#pragma unroll
    for (int t = 0; t < 4; t++) {
      float g = fast_gelu(v[t] + bi);
      act[(size_t)(row + t) * MLP_HID + col] = __float2bfloat16(g);
    }
  }
};

struct PartEpi {  // split-K fp32 partial store (N = D_MODEL)
  float* part;
  __device__ void operator()(int row, int col, const floatx4& v) const {
    float* p = part + (size_t)blockIdx.z * ((size_t)M_TOTAL * D_MODEL) +
               (size_t)row * D_MODEL + col;
#pragma unroll
    for (int t = 0; t < 4; t++) p[(size_t)t * D_MODEL] = v[t];
  }
};

struct PartBf16Epi {  // split-K bf16 partial store (N = IN_DIM)
  __hip_bfloat16* part;
  __device__ void operator()(int row, int col, const floatx4& v) const {
    __hip_bfloat16* p = part + (size_t)blockIdx.z * ((size_t)M_TOTAL * IN_DIM) +
                        (size_t)row * IN_DIM + col;
#pragma unroll
    for (int t = 0; t < 4; t++) p[(size_t)t * IN_DIM] = __float2bfloat16(v[t]);
  }
};

// ---------------------------------------------------------------- GEMM 128x128
// C[M,N] = A[M,K] @ B[K,N], A row-major bf16, B given as B^T [N][K] bf16.
// 128x128 tile, BK=64 (32 KB LDS), 256 threads = 4 waves (2x2), wave does
// 64x64 via 4x4 mfma_f32_16x16x32_bf16 frags. XOR-swizzled staging via
// global_load_lds. ~3 blocks/CU; cross-block wave overlap hides barrier drains.
// Used for embed/kqv/ao (measured best for grids >= 512 blocks; 256^2 swap
// measured worse R2/R3; XCD swizzle refuted R8).

template <class Epi>
__global__ __launch_bounds__(256) void k_gemm(const __hip_bfloat16* __restrict__ A,
                                              const __hip_bfloat16* __restrict__ Bt,
                                              int M, int N, int K, int Kchunk, Epi epi) {
  __shared__ __align__(16) short As[128 * 64];
  __shared__ __align__(16) short Bs[128 * 64];
  const int tid  = threadIdx.x;
  const int lane = tid & 63;
  const int w    = tid >> 6;
  const int wm   = (w >> 1) << 6;
  const int wn   = (w & 1) << 6;
  const int r    = lane & 15;
  const int quad = lane >> 4;
  const int m0 = blockIdx.y << 7;
  const int n0 = blockIdx.x << 7;
  const int koff = blockIdx.z * Kchunk;

  const __hip_bfloat16* pa[4];
  const __hip_bfloat16* pb[4];
#pragma unroll
  for (int j = 0; j < 4; j++) {
    int s = tid + j * 256;
    int row = s >> 3;
    int c = (s & 7) ^ (row & 7);
    pa[j] = A  + (size_t)(m0 + row) * K + (c << 3) + koff;
    pb[j] = Bt + (size_t)(n0 + row) * K + (c << 3) + koff;
  }

  floatx4 acc[4][4];
#pragma unroll
  for (int i = 0; i < 4; i++)
#pragma unroll
    for (int j = 0; j < 4; j++) acc[i][j] = (floatx4){0.f, 0.f, 0.f, 0.f};

  int aoff[2][4], boff[2][4];
#pragma unroll
  for (int kk = 0; kk < 2; kk++)
#pragma unroll
    for (int i = 0; i < 4; i++) {
      int pc = ((quad + (kk << 2)) ^ (r & 7)) << 3;
      aoff[kk][i] = (wm + i * 16 + r) * 64 + pc;
      boff[kk][i] = (wn + i * 16 + r) * 64 + pc;
    }

  for (int k0 = 0; k0 < Kchunk; k0 += 64) {
    __syncthreads();
#pragma unroll
    for (int j = 0; j < 4; j++) {
      async_copy16(pa[j] + k0, &As[(tid + j * 256) * 8]);
      async_copy16(pb[j] + k0, &Bs[(tid + j * 256) * 8]);
    }
    __syncthreads();
#pragma unroll
    for (int kk = 0; kk < 2; kk++) {
      short8 fa[4], fb[4];
#pragma unroll
      for (int i = 0; i < 4; i++) {
        fa[i] = *(const short8*)&As[aoff[kk][i]];
        fb[i] = *(const short8*)&Bs[boff[kk][i]];
      }
#pragma unroll
      for (int i = 0; i < 4; i++)
#pragma unroll
        for (int j = 0; j < 4; j++)
          acc[i][j] = __builtin_amdgcn_mfma_f32_16x16x32_bf16(fa[i], fb[j], acc[i][j], 0, 0, 0);
    }
  }

#pragma unroll
  for (int i = 0; i < 4; i++)
#pragma unroll
    for (int j = 0; j < 4; j++)
      epi(m0 + wm + i * 16 + quad * 4, n0 + wn + j * 16 + r, acc[i][j]);
}

template <class Epi>
static void launch_gemm(const __hip_bfloat16* A, const __hip_bfloat16* Bt,
                        int M, int N, int K, Epi epi, hipStream_t s) {
  dim3 grid(N / 128, M / 128, 1);
  k_gemm<Epi><<<grid, 256, 0, s>>>(A, Bt, M, N, K, K, epi);
}

// ---------------------------------------------------------------- GEMM 256x256 (8-phase)
// Used for FC + proj. Register-pinned: VGPR 120 + 128 AGPR acc = 248/256 --
// max 2 waves/SIMD, 1 block/CU (LDS 128KB); no deeper lookahead or phase
// rebalance fits the register budget (verified: +16 VGPR => 1 wave/SIMD cliff).

#define STAGE_A(BUF, H, KT)                                                       \
  do {                                                                            \
    async_copy16(ga + (size_t)((H) * 128) * K + (KT) * 64,                        \
                 &As[BUF][(tid + (H) * 1024) * 8]);                               \
    async_copy16(ga + (size_t)((H) * 128 + 64) * K + (KT) * 64,                   \
                 &As[BUF][(tid + (H) * 1024 + 512) * 8]);                         \
  } while (0)

#define STAGE_B(BUF, H, KT)                                                       \
  do {                                                                            \
    async_copy16(gb + (size_t)((H) * 128) * K + (KT) * 64,                        \
                 &Bs[BUF][(tid + (H) * 1024) * 8]);                               \
    async_copy16(gb + (size_t)((H) * 128 + 64) * K + (KT) * 64,                   \
                 &Bs[BUF][(tid + (H) * 1024 + 512) * 8]);                         \
  } while (0)

#define MFMA_BLK(IO, JO, BFX)                                                     \
  _Pragma("unroll") for (int i = 0; i < 4; i++) {                                 \
    _Pragma("unroll") for (int j = 0; j < 2; j++) {                               \
      acc[(IO) + i][(JO) + j] = __builtin_amdgcn_mfma_f32_16x16x32_bf16(          \
          af[i][0], BFX[j][0], acc[(IO) + i][(JO) + j], 0, 0, 0);                 \
      acc[(IO) + i][(JO) + j] = __builtin_amdgcn_mfma_f32_16x16x32_bf16(          \
          af[i][1], BFX[j][1], acc[(IO) + i][(JO) + j], 0, 0, 0);                 \
    }                                                                             \
  }

#define GTILE(T, BUF)                                                             \
  {                                                                               \
    _Pragma("unroll") for (int i = 0; i < 4; i++) {                               \
      af[i][0] = *(const short8*)&As[BUF][arb[i] + pc0];                          \
      af[i][1] = *(const short8*)&As[BUF][arb[i] + pc1];                          \
    }                                                                             \
    _Pragma("unroll") for (int j = 0; j < 2; j++) {                               \
      bf0[j][0] = *(const short8*)&Bs[BUF][brb[j] + pc0];                         \
      bf0[j][1] = *(const short8*)&Bs[BUF][brb[j] + pc1];                         \
    }                                                                             \
    if ((T) + 1 < nt) { STAGE_A((BUF) ^ 1, 1, (T) + 1); }                         \
    __builtin_amdgcn_s_barrier();                                                 \
    asm volatile("s_waitcnt lgkmcnt(0)" ::: "memory");                            \
    __builtin_amdgcn_s_setprio(1);                                                \
    MFMA_BLK(0, 0, bf0)                                                           \
    __builtin_amdgcn_s_setprio(0);                                                \
    __builtin_amdgcn_s_barrier();                                                 \
    _Pragma("unroll") for (int j = 0; j < 2; j++) {                               \
      bf1[j][0] = *(const short8*)&Bs[BUF][brb[j] + 8192 + pc0];                  \
      bf1[j][1] = *(const short8*)&Bs[BUF][brb[j] + 8192 + pc1];                  \
    }                                                                             \
    if ((T) + 2 < nt) { STAGE_A(BUF, 0, (T) + 2); }                               \
    __builtin_amdgcn_s_barrier();                                                 \
    asm volatile("s_waitcnt lgkmcnt(0)" ::: "memory");                            \
    __builtin_amdgcn_s_setprio(1);                                                \
    MFMA_BLK(0, 2, bf1)                                                           \
    __builtin_amdgcn_s_setprio(0);                                                \
    __builtin_amdgcn_s_barrier();                                                 \
    _Pragma("unroll") for (int i = 0; i < 4; i++) {                               \
      af[i][0] = *(const short8*)&As[BUF][arb[i] + 8192 + pc0];                   \
      af[i][1] = *(const short8*)&As[BUF][arb[i] + 8192 + pc1];                   \
    }                                                                             \
    if ((T) + 2 < nt) { STAGE_B(BUF, 0, (T) + 2); }                               \
    __builtin_amdgcn_s_barrier();                                                 \
    asm volatile("s_waitcnt lgkmcnt(0)" ::: "memory");                            \
    __builtin_amdgcn_s_setprio(1);                                                \
    MFMA_BLK(4, 0, bf0)                                                           \
    __builtin_amdgcn_s_setprio(0);                                                \
    __builtin_amdgcn_s_barrier();                                                 \
    if ((T) + 2 < nt) { STAGE_B(BUF, 1, (T) + 2); }                               \
    __builtin_amdgcn_s_setprio(1);                                                \
    MFMA_BLK(4, 2, bf1)                                                           \
    __builtin_amdgcn_s_setprio(0);                                                \
    if ((T) + 2 < nt) {                                                           \
      asm volatile("s_waitcnt vmcnt(6)" ::: "memory");                            \
    } else {                                                                      \
      asm volatile("s_waitcnt vmcnt(0)" ::: "memory");                            \
    }                                                                             \
    __builtin_amdgcn_s_barrier();                                                 \
  }

template <class Epi>
__global__ __launch_bounds__(512, 2) void k_gemm256(const __hip_bfloat16* __restrict__ A,
                                                    const __hip_bfloat16* __restrict__ Bt,
                                                    int M, int N, int K, int Kchunk, Epi epi) {
  (void)M; (void)N;
  __shared__ __align__(16) short As[2][16384];   // 2 x 32 KB
  __shared__ __align__(16) short Bs[2][16384];   // 2 x 32 KB
  const int tid  = threadIdx.x;
  const int lane = tid & 63;
  const int w    = tid >> 6;        // 0..7
  const int wr   = w >> 2;          // 0..1
  const int wc   = w & 3;           // 0..3
  const int r    = lane & 15;
  const int quad = lane >> 4;
  const int m0 = blockIdx.y << 8;
  const int n0 = blockIdx.x << 8;
  const int koff = blockIdx.z * Kchunk;
  const int nt = Kchunk >> 6;       // K-tiles; must be even

  const int sr = tid >> 3;                     // 0..63
  const int sc = (tid & 7) ^ (sr & 7);
  const __hip_bfloat16* ga = A  + (size_t)(m0 + sr) * K + sc * 8 + koff;
  const __hip_bfloat16* gb = Bt + (size_t)(n0 + sr) * K + sc * 8 + koff;

  const int pc0 = ((quad    ) ^ (r & 7)) << 3;
  const int pc1 = ((quad + 4) ^ (r & 7)) << 3;
  int arb[4], brb[2];
#pragma unroll
  for (int i = 0; i < 4; i++) arb[i] = ((2 * i + wr) * 16 + r) * 64;
#pragma unroll
  for (int j = 0; j < 2; j++) brb[j] = ((4 * j + wc) * 16 + r) * 64;

  floatx4 acc[8][4];
#pragma unroll
  for (int i = 0; i < 8; i++)
#pragma unroll
    for (int j = 0; j < 4; j++) acc[i][j] = (floatx4){0.f, 0.f, 0.f, 0.f};
  short8 af[4][2], bf0[2][2], bf1[2][2];

  STAGE_A(0, 0, 0);
  STAGE_B(0, 0, 0);
  STAGE_B(0, 1, 0);
  STAGE_A(0, 1, 0);
  if (nt > 1) {
    STAGE_A(1, 0, 1);
    STAGE_B(1, 0, 1);
    STAGE_B(1, 1, 1);
    asm volatile("s_waitcnt vmcnt(6)" ::: "memory");
  } else {
    asm volatile("s_waitcnt vmcnt(0)" ::: "memory");
  }
  __builtin_amdgcn_s_barrier();

  for (int t = 0; t < nt; t += 2) {
    GTILE(t, 0)
    GTILE(t + 1, 1)
  }

#pragma unroll
  for (int i = 0; i < 8; i++)
#pragma unroll
    for (int j = 0; j < 4; j++)
      epi(m0 + (2 * i + wr) * 16 + quad * 4, n0 + (4 * j + wc) * 16 + r, acc[i][j]);
}

// ---------------------------------------------------------------- flash attention
// v4 (converged): 256 threads = 4 waves, wave owns 16 q-rows, block = 64
// q-rows -> 1024 blocks (32 strips x 32 bh): fine-grained longest-first
// packing + ~3 blocks/CU resident for cross-block overlap; barriers sync only
// 4 waves; every tile live for every wave. Double-buffered K/V via
// global_load_lds; counted vmcnt(4) pipeline, never drains to 0 mid-loop.
// XOR-swizzle; S^T = K Q^T, p=exp(s) (scores bounded), deferred l; P^T via
// per-wave LDS; O^T += V^T P^T. (QK/PV interleave refuted R6/R10.)

#define PSTR 68   // bf16 elems per q-row in P buffer

#define STAGE_KV(T, P)                                                         \
  do {                                                                         \
    async_copy16(kp + (size_t)((((T) << 6)) + row0) * HEAD_DIM + g0 * 8,       \
                 &Ks[P][c0 * 8]);                                              \
    async_copy16(kp + (size_t)((((T) << 6)) + row1) * HEAD_DIM + g1 * 8,       \
                 &Ks[P][c1 * 8]);                                              \
    async_copy16(vp + (size_t)row0 * SEQ_LEN + ((T) << 6) + g0 * 8,            \
                 &Vs[P][c0 * 8]);                                              \
    async_copy16(vp + (size_t)row1 * SEQ_LEN + ((T) << 6) + g1 * 8,            \
                 &Vs[P][c1 * 8]);                                              \
  } while (0)

#define QKSUB(KT, P)                                                           \
  {                                                                            \
    const int tss = ts + ((KT) << 4);                                          \
    short4v pk0;                                                               \
    if (tss < qend) {                                                          \
      const int krow = ((KT) << 4) + r;                                        \
      short8 a0 = *(const short8*)&Ks[P][(krow * 8 + (quad ^ sw)) * 8];        \
      short8 a1 = *(const short8*)&Ks[P][(krow * 8 + ((quad ^ sw) ^ 4)) * 8];  \
      floatx4 s0 = (floatx4){0.f, 0.f, 0.f, 0.f};                              \
      s0 = __builtin_amdgcn_mfma_f32_16x16x32_bf16(a0, qf0, s0, 0, 0, 0);      \
      s0 = __builtin_amdgcn_mfma_f32_16x16x32_bf16(a1, qf1, s0, 0, 0, 0);      \
      if (tss + 15 > qbw) {                                                    \
        int off0 = qbw + r - tss;                                              \
        _Pragma("unroll") for (int tt = 0; tt < 4; tt++) {                     \
          int kl = (quad << 2) + tt;                                           \
          if (kl > off0) s0[tt] = -INFINITY;                                   \
        }                                                                      \
      }                                                                        \
      _Pragma("unroll") for (int tt = 0; tt < 4; tt++) {                       \
        float e0 = __expf(s0[tt]); ls0 += e0;                                  \
        ((__hip_bfloat16*)&pk0)[tt] = __float2bfloat16(e0);                    \
      }                                                                        \
    } else {                                                                   \
      pk0 = (short4v){0, 0, 0, 0};                                             \
    }                                                                          \
    *(short4v*)(pw + r * PSTR + ((KT) << 4) + (quad << 2)) = pk0;              \
  }

#define ATILE(T, P)                                                            \
  {                                                                            \
    const int ts = (T) << 6;                                                   \
    QKSUB(0, P)                                                                \
    QKSUB(1, P)                                                                \
    QKSUB(2, P)                                                                \
    QKSUB(3, P)                                                                \
    __builtin_amdgcn_s_setprio(1);                                             \
    _Pragma("unroll") for (int c = 0; c < 2; c++) {                            \
      short8 pb0 = *(const short8*)(pw + r * PSTR + (c << 5) + (quad << 3));   \
      _Pragma("unroll") for (int fd = 0; fd < 4; fd++) {                       \
        const int vrow = (fd << 4) + r;                                        \
        short8 va = *(const short8*)&Vs[P][(vrow * 8 + (((c << 2) + quad) ^ sw)) * 8]; \
        of[fd] = __builtin_amdgcn_mfma_f32_16x16x32_bf16(va, pb0, of[fd], 0, 0, 0); \
      }                                                                        \
    }                                                                          \
    __builtin_amdgcn_s_setprio(0);                                             \
    __builtin_amdgcn_s_barrier();                                              \
    if ((T) + 2 < ktiles) {                                                    \
      STAGE_KV((T) + 2, P);                                                    \
      asm volatile("s_waitcnt vmcnt(4)" ::: "memory");                         \
    } else {                                                                   \
      asm volatile("s_waitcnt vmcnt(0)" ::: "memory");                         \
    }                                                                          \
    __builtin_amdgcn_s_barrier();                                              \
    __builtin_amdgcn_sched_barrier(0);                                         \
  }

__global__ __launch_bounds__(256, 3) void k_flash_attn(const __hip_bfloat16* __restrict__ kb,
                                                       const __hip_bfloat16* __restrict__ qb,
                                                       const __hip_bfloat16* __restrict__ vtb,
                                                       __hip_bfloat16* __restrict__ ob) {
  __shared__ __align__(16) short Ks[2][64 * 64];         // 16 KB
  __shared__ __align__(16) short Vs[2][64 * 64];         // 16 KB
  __shared__ __align__(16) __hip_bfloat16 Pb[4][16 * PSTR];  // 8.5 KB
  const int tid  = threadIdx.x;
  const int lane = tid & 63;
  const int w    = tid >> 6;                         // 0..3
  const int r    = lane & 15;
  const int quad = lane >> 4;
  const int sw   = r & 7;
  const int bh    = blockIdx.x & 31;                 // 32 (b,h)
  const int strip = (SEQ_LEN / 64 - 1) - (blockIdx.x >> 5);  // longest first
  const int qb0   = strip << 6;                      // block q start (64 rows)
  const int qbw   = qb0 + (w << 4);                  // wave q start (16 rows)
  const int qend  = qbw + 16;
  const int b = bh >> 4, h = bh & (N_HEAD - 1);

  const __hip_bfloat16* qp = qb  + ((size_t)bh * SEQ_LEN + qbw) * HEAD_DIM;
  const __hip_bfloat16* kp = kb  + (size_t)bh * SEQ_LEN * HEAD_DIM;
  const __hip_bfloat16* vp = vtb + (size_t)bh * HEAD_DIM * SEQ_LEN;  // [d][l]
  __hip_bfloat16* pw = &Pb[w][0];

  short8 qf0 = *(const short8*)(qp + r * HEAD_DIM + quad * 8);
  short8 qf1 = *(const short8*)(qp + r * HEAD_DIM + quad * 8 + 32);

  floatx4 of[4];
#pragma unroll
  for (int i = 0; i < 4; i++) of[i] = (floatx4){0.f, 0.f, 0.f, 0.f};
  float ls0 = 0.f;

  // staging: thread tid stages chunks tid and tid+256 of each 64x64 tile
  const int c0 = tid, c1 = tid + 256;
  const int row0 = c0 >> 3, g0 = (c0 & 7) ^ (row0 & 7);
  const int row1 = c1 >> 3, g1 = (c1 & 7) ^ (row1 & 7);

  const int ktiles = strip + 1;   // may be odd
  STAGE_KV(0, 0);
  if (ktiles > 1) {
    STAGE_KV(1, 1);
    asm volatile("s_waitcnt vmcnt(4)" ::: "memory");
  } else {
    asm volatile("s_waitcnt vmcnt(0)" ::: "memory");
  }
  __builtin_amdgcn_s_barrier();
  __builtin_amdgcn_sched_barrier(0);

  for (int t = 0; t < ktiles; t += 2) {
    ATILE(t, 0)
    if (t + 1 < ktiles) { ATILE(t + 1, 1) }
  }

  ls0 += __shfl_xor(ls0, 16); ls0 += __shfl_xor(ls0, 32);
  float inv0 = 1.f / ls0;

  size_t orow = ((size_t)b * SEQ_LEN + qbw + r) * D_MODEL + (size_t)h * HEAD_DIM;
#pragma unroll
  for (int fd = 0; fd < 4; fd++) {
    short4v o4;
#pragma unroll
    for (int tt = 0; tt < 4; tt++)
      ((__hip_bfloat16*)&o4)[tt] = __float2bfloat16(of[fd][tt] * inv0);
    *(short4v*)(ob + orow + fd * 16 + quad * 4) = o4;
  }
}

// ---------------------------------------------------------------- driver

extern "C" void kernel_launch(void* const* d_in, const int* in_sizes, int n_in,
                              void* d_out, int out_size, void* d_ws, size_t ws_size,
                              hipStream_t stream) {
  (void)in_sizes; (void)n_in; (void)out_size; (void)ws_size;
  const float* x      = (const float*)d_in[0];
  const float* wte_w  = (const float*)d_in[1];
  const float* wte_b  = (const float*)d_in[2];
  const float* wpe    = (const float*)d_in[3];
  const float* ln1_w  = (const float*)d_in[4];
  const float* ln1_b  = (const float*)d_in[5];
  const float* kq_w   = (const float*)d_in[6];
  const float* kq_b   = (const float*)d_in[7];
  const float* v_w    = (const float*)d_in[8];
  const float* v_b    = (const float*)d_in[9];
  const float* ao_w   = (const float*)d_in[10];
  const float* ao_b   = (const float*)d_in[11];
  const float* ln2_w  = (const float*)d_in[12];
  const float* ln2_b  = (const float*)d_in[13];
  const float* fc_w   = (const float*)d_in[14];
  const float* fc_b   = (const float*)d_in[15];
  const float* proj_w = (const float*)d_in[16];
  const float* proj_b = (const float*)d_in[17];

  float* out0     = (float*)d_out;                                  // (B,L,512)
  float* attn_out = out0 + (size_t)M_TOTAL * IN_DIM;                // (B,L,1024)

  char* ws = (char*)d_ws;
  // layout (MB): wT_all [0,22) | x_bf [22,26) | R1 [26,58) | k [58,66) |
  //              q [66,74) | vt [74,82) | o [82,90) | hn [90,98)
  __hip_bfloat16* wT    = (__hip_bfloat16*)ws;
  __hip_bfloat16* x_bf  = (__hip_bfloat16*)(ws + 22 * 1048576);
  char* R1              = ws + 26 * 1048576;                         // embed_part / ao_part / act
  float* embed_part     = (float*)R1;
  float* ao_part        = (float*)R1;
  __hip_bfloat16* act   = (__hip_bfloat16*)R1;
  __hip_bfloat16* k_bf  = (__hip_bfloat16*)(ws + 58 * 1048576);
  __hip_bfloat16* q_bf  = (__hip_bfloat16*)(ws + 66 * 1048576);
  __hip_bfloat16* vt_bf = (__hip_bfloat16*)(ws + 74 * 1048576);
  __hip_bfloat16* o_bf  = (__hip_bfloat16*)(ws + 82 * 1048576);
  __hip_bfloat16* hn_bf = (__hip_bfloat16*)(ws + 90 * 1048576);
  __hip_bfloat16* xo_bf = k_bf;                                      // k dead after attn
  __hip_bfloat16* proj_part = k_bf;                                  // 32 MB over k/q/vt/o (dead at step 9)

  // wT sub-offsets (bf16 elements)
  __hip_bfloat16* wteT  = wT;            // [512][1024]^T  -> [1024][512]
  __hip_bfloat16* kqvT  = wT +  524288;  // kq^T [2048][1024] then v^T [1024][1024] (contiguous)
  __hip_bfloat16* aoT   = wT + 3670016;
  __hip_bfloat16* fcT   = wT + 4718592;
  __hip_bfloat16* projT = wT + 8912896;

  // 1. fused prep: all 6 weight transposes + x convert (inputs only)
  k_prep<<<4736, 256, 0, stream>>>(wte_w, kq_w, v_w, ao_w, fc_w, proj_w, x, wT, x_bf);

  // 2. embed GEMM: split-K x2 fp32 partials
  {
    dim3 grid(D_MODEL / 128, M_TOTAL / 128, 2);
    k_gemm<PartEpi><<<grid, 256, 0, stream>>>(x_bf, wteT, M_TOTAL, D_MODEL, IN_DIM, IN_DIM / 2,
                                              PartEpi{embed_part});
  }

  // 3. hn = LN1(part0 + part1 + wte_b + wpe)
  k_ln1_combine<<<M_TOTAL, 256, 0, stream>>>(embed_part, wte_b, wpe, ln1_w, ln1_b, hn_bf);

  // 4. fused kqv = hn @ [kq_w | v_w]  (N=3072, 768 blocks); V^T written directly
  launch_gemm(hn_bf, kqvT, M_TOTAL, 3 * D_MODEL, D_MODEL,
              KQVEpi{kq_b, v_b, k_bf, q_bf, vt_bf}, stream);

  // 5. flash attention -> o  [b,l,h*d] bf16  (64-row blocks, 1024 blocks)
  k_flash_attn<<<(SEQ_LEN / 64) * 32, 256, 0, stream>>>(k_bf, q_bf, vt_bf, o_bf);

  // 6. ao GEMM: split-K x2 fp32 partials
  {
    dim3 grid(D_MODEL / 128, M_TOTAL / 128, 2);
    k_gemm<PartEpi><<<grid, 256, 0, stream>>>(o_bf, aoT, M_TOTAL, D_MODEL, D_MODEL, D_MODEL / 2,
                                              PartEpi{ao_part});
  }

  // 7. attn_out = part0+part1+ao_b+hn (to d_out); xo = LN2(attn_out)
  k_ln2_combine<<<M_TOTAL, 256, 0, stream>>>(ao_part, ao_b, hn_bf, ln2_w, ln2_b, attn_out, xo_bf);

  // 8. act = gelu(xo @ fc_w + fc_b)   (256^2 8-phase, 256 blocks, nt=16)
  {
    dim3 grid(MLP_HID / 256, M_TOTAL / 256, 1);
    k_gemm256<FCEpi><<<grid, 512, 0, stream>>>(xo_bf, fcT, M_TOTAL, MLP_HID, D_MODEL, D_MODEL,
                                               FCEpi{fc_b, act});
  }

  // 9. out = act @ proj_w + proj_b  (256^2 8-phase, split-K x8 bf16 partials; nt=8)
  {
    dim3 grid(IN_DIM / 256, M_TOTAL / 256, 8);
    k_gemm256<PartBf16Epi><<<grid, 512, 0, stream>>>(act, projT, M_TOTAL, IN_DIM, MLP_HID,
                                                     MLP_HID / 8, PartBf16Epi{proj_part});
  }
  k_reduce_proj<<<M_TOTAL * IN_DIM / 8 / 256, 256, 0, stream>>>(proj_part, proj_b, out0);
}